// Round 13
// baseline (1497.769 us; speedup 1.0000x reference)
//
#include <hip/hip_runtime.h>
#include <hip/hip_bf16.h>
#include <math.h>

// Problem dims (fixed by the reference)
#define NB 64      // batch
#define NS 64      // encoder steps
#define NL 64      // decoder steps
#define NH 256     // hidden
#define G3 768     // 3*NH (gates r,z,n)
#define NVIN 10000
#define NVOUT 10000
#define KP2 10240   // NVIN padded (4 splits x 40 x BK=64)
#define NOUTP 10112 // NVOUT padded to 128 for out GEMM

typedef __attribute__((ext_vector_type(8))) short bf16x8;  // 8 bf16 (4 VGPRs)
typedef __attribute__((ext_vector_type(4))) float f32x4;   // MFMA accumulator
typedef __attribute__((ext_vector_type(4))) unsigned int u32x4;

// async global->LDS, 16B per lane (dest must be wave-uniform base + lane*16)
__device__ __forceinline__ void gld_lds16(const __hip_bfloat16* g, __hip_bfloat16* l) {
  __builtin_amdgcn_global_load_lds(
      (const __attribute__((address_space(1))) unsigned int*)(const void*)g,
      (__attribute__((address_space(3))) unsigned int*)(void*)l, 16, 0, 0);
}

__device__ __forceinline__ unsigned int f2bf(float f) {  // RNE fp32->bf16 bits
  unsigned int u = __float_as_uint(f);
  return (u + 0x7fff + ((u >> 16) & 1)) >> 16;
}
__device__ __forceinline__ float bf2f(unsigned short u) {
  return __uint_as_float((unsigned)u << 16);
}
__device__ __forceinline__ float fast_tanh(float x) {
  float e = __expf(-2.f * x);
  return (1.f - e) / (1.f + e);
}
// Workgroup barrier WITHOUT the vmcnt(0) drain __syncthreads() emits.
__device__ __forceinline__ void lds_barrier() {
  asm volatile("s_waitcnt lgkmcnt(0)\n\ts_barrier" ::: "memory");
}

// ---------------------------------------------------------------------------
// fp32 -> bf16 convert with padding; swz=1 pre-swizzles columns within each
// 64-group by ((row&7)<<3) (T2/m173: swizzle SOURCE, LDS dest linear).
// ---------------------------------------------------------------------------
__global__ __launch_bounds__(256) void k_cvt_pad(
    const float* __restrict__ in, __hip_bfloat16* __restrict__ out,
    int in_rows, int in_cols, int out_cols, int swz) {
  int r = blockIdx.x;
  const float* src = in + (size_t)r * in_cols;
  __hip_bfloat16* dst = out + (size_t)r * out_cols;
  bool live = r < in_rows;
  int sx = swz ? ((r & 7) << 3) : 0;
  for (int c = threadIdx.x * 4; c < out_cols; c += 1024) {
    int cc = (c & ~63) | ((c & 63) ^ sx);
    __hip_bfloat16 v[4];
    if (live && cc + 3 < in_cols) {
      float4 f = *(const float4*)(src + cc);
      v[0] = __float2bfloat16(f.x); v[1] = __float2bfloat16(f.y);
      v[2] = __float2bfloat16(f.z); v[3] = __float2bfloat16(f.w);
    } else {
      v[0] = v[1] = v[2] = v[3] = __float2bfloat16(0.f);
    }
    *(ushort4*)(dst + c) = *(const ushort4*)v;
  }
}

// ---------------------------------------------------------------------------
// Pack recurrent weights to bf16 Wcat[f][c][k].
// ---------------------------------------------------------------------------
__global__ __launch_bounds__(256) void k_wpack(
    const float* __restrict__ srcA, int strideA,
    const float* __restrict__ srcB, int strideB,
    __hip_bfloat16* __restrict__ out, int total) {
  int idx = blockIdx.x * 256 + threadIdx.x;
  if (idx >= total) return;
  int k = idx & 255, c = (idx >> 8) & 255, f = idx >> 16;
  float v = (f < 3) ? srcA[(size_t)(f * 256 + c) * strideA + k]
                    : srcB[(size_t)((f - 3) * 256 + c) * strideB + k];
  out[idx] = __float2bfloat16(v);
}

// ---------------------------------------------------------------------------
// Enc GEMM, split-K (see R7): P[z] partials, reduced by k_reduce4.
// ---------------------------------------------------------------------------
__global__ __launch_bounds__(256) void k_gemm_encS(
    const __hip_bfloat16* __restrict__ A, const __hip_bfloat16* __restrict__ B,
    float* __restrict__ P) {
  __shared__ __hip_bfloat16 As[128][64];
  __shared__ __hip_bfloat16 Bs[128][64];
  int t = threadIdx.x;
  int wid = t >> 6, lane = t & 63;
  int m0 = blockIdx.y * 128, n0 = blockIdx.x * 128;
  int wr = wid >> 1, wc = wid & 1;
  int r16 = lane & 15, hi16 = lane >> 4;
  int xr = (r16 & 7) << 4;
  f32x4 acc[4][4] = {};
  int kbeg = blockIdx.z * 2560;
  for (int ks = 0; ks < 40; ++ks) {
    int k0 = kbeg + ks * 64;
    __syncthreads();
#pragma unroll
    for (int is = 0; is < 4; ++is) {
      int off = is * 4096 + t * 16;
      int r = off >> 7, e = (off & 127) >> 1;
      gld_lds16(A + (size_t)(m0 + r) * KP2 + k0 + e, &As[r][e]);
      gld_lds16(B + (size_t)(n0 + r) * KP2 + k0 + e, &Bs[r][e]);
    }
    __syncthreads();
    const char* ab = (const char*)As;
    const char* bb = (const char*)Bs;
#pragma unroll
    for (int kk = 0; kk < 2; ++kk) {
      int ko = kk * 64 + hi16 * 16;
      bf16x8 af[4], bfr[4];
#pragma unroll
      for (int i = 0; i < 4; ++i) {
        af[i]  = *(const bf16x8*)(ab + (wr * 64 + i * 16 + r16) * 128 + (ko ^ xr));
        bfr[i] = *(const bf16x8*)(bb + (wc * 64 + i * 16 + r16) * 128 + (ko ^ xr));
      }
#pragma unroll
      for (int i = 0; i < 4; ++i)
#pragma unroll
        for (int j = 0; j < 4; ++j)
          acc[i][j] = __builtin_amdgcn_mfma_f32_16x16x32_bf16(af[i], bfr[j], acc[i][j], 0, 0, 0);
    }
  }
  float* Pz = P + (size_t)blockIdx.z * 4096 * G3;
#pragma unroll
  for (int i = 0; i < 4; ++i)
#pragma unroll
    for (int j = 0; j < 4; ++j) {
      int ccol = n0 + wc * 64 + j * 16 + r16;
#pragma unroll
      for (int q = 0; q < 4; ++q) {
        int crow = m0 + wr * 64 + i * 16 + hi16 * 4 + q;
        Pz[(size_t)crow * G3 + ccol] = acc[i][j][q];
      }
    }
}

// Gienc(bf16) = P0+P1+P2+P3 + bias
__global__ __launch_bounds__(256) void k_reduce4(
    const float4* __restrict__ P, const float* __restrict__ bias,
    ushort4* __restrict__ G) {
  int idx = blockIdx.x * 256 + threadIdx.x;
  float4 a = P[idx], b = P[idx + 786432], c = P[idx + 2 * 786432],
         d = P[idx + 3 * 786432];
  float4 bs = *(const float4*)(bias + (idx % 192) * 4);
  ushort4 o;
  o.x = (unsigned short)f2bf(a.x + b.x + c.x + d.x + bs.x);
  o.y = (unsigned short)f2bf(a.y + b.y + c.y + d.y + bs.y);
  o.z = (unsigned short)f2bf(a.z + b.z + c.z + d.z + bs.z);
  o.w = (unsigned short)f2bf(a.w + b.w + c.w + d.w + bs.w);
  G[idx] = o;
}

// ---------------------------------------------------------------------------
// Out GEMM (BK=64 + swizzle, see R7).
// ---------------------------------------------------------------------------
__global__ __launch_bounds__(256) void k_gemm_outS(
    const __hip_bfloat16* __restrict__ A, const __hip_bfloat16* __restrict__ B,
    const float* __restrict__ bias, float* __restrict__ C) {
  __shared__ __hip_bfloat16 As[128][64];
  __shared__ __hip_bfloat16 Bs[128][64];
  int t = threadIdx.x;
  int wid = t >> 6, lane = t & 63;
  int m0 = blockIdx.y * 128, n0 = blockIdx.x * 128;
  int wr = wid >> 1, wc = wid & 1;
  int r16 = lane & 15, hi16 = lane >> 4;
  int xr = (r16 & 7) << 4;
  f32x4 acc[4][4] = {};
  for (int k0 = 0; k0 < NH; k0 += 64) {
    __syncthreads();
#pragma unroll
    for (int is = 0; is < 4; ++is) {
      int off = is * 4096 + t * 16;
      int r = off >> 7, e = (off & 127) >> 1;
      gld_lds16(A + (size_t)(m0 + r) * NH + k0 + e, &As[r][e]);
      gld_lds16(B + (size_t)(n0 + r) * NH + k0 + e, &Bs[r][e]);
    }
    __syncthreads();
    const char* ab = (const char*)As;
    const char* bb = (const char*)Bs;
#pragma unroll
    for (int kk = 0; kk < 2; ++kk) {
      int ko = kk * 64 + hi16 * 16;
      bf16x8 af[4], bfr[4];
#pragma unroll
      for (int i = 0; i < 4; ++i) {
        af[i]  = *(const bf16x8*)(ab + (wr * 64 + i * 16 + r16) * 128 + (ko ^ xr));
        bfr[i] = *(const bf16x8*)(bb + (wc * 64 + i * 16 + r16) * 128 + (ko ^ xr));
      }
#pragma unroll
      for (int i = 0; i < 4; ++i)
#pragma unroll
        for (int j = 0; j < 4; ++j)
          acc[i][j] = __builtin_amdgcn_mfma_f32_16x16x32_bf16(af[i], bfr[j], acc[i][j], 0, 0, 0);
    }
  }
#pragma unroll
  for (int i = 0; i < 4; ++i)
#pragma unroll
    for (int j = 0; j < 4; ++j) {
      int ccol = n0 + wc * 64 + j * 16 + r16;
      if (ccol < NVOUT) {
        float bs = bias[ccol];
#pragma unroll
        for (int q = 0; q < 4; ++q) {
          int crow = m0 + wr * 64 + i * 16 + hi16 * 4 + q;  // = l*64+b
          int l = crow >> 6, b = crow & 63;
          C[((size_t)b * NL + l) * NVOUT + ccol] = acc[i][j][q] + bs;
        }
      }
    }
}

// ---------------------------------------------------------------------------
// ENCW GEMM (plain rows): ENCW[b*64+s][c] = sum_k ench[b*64+s][k]*Wih_ctx[c][k]
// ---------------------------------------------------------------------------
__global__ __launch_bounds__(256) void k_gemm_encw(
    const __hip_bfloat16* __restrict__ A, const __hip_bfloat16* __restrict__ B,
    __hip_bfloat16* __restrict__ C) {
  __shared__ __hip_bfloat16 As[128][32];
  __shared__ __hip_bfloat16 Bs[128][32];
  int t = threadIdx.x;
  int wid = t >> 6, lane = t & 63;
  int m0 = blockIdx.y * 128, n0 = blockIdx.x * 128;
  int wr = wid >> 1, wc = wid & 1;
  f32x4 acc[4][4] = {};
  for (int k0 = 0; k0 < NH; k0 += 32) {
    __syncthreads();
#pragma unroll
    for (int is = 0; is < 2; ++is) {
      int off = is * 4096 + wid * 1024 + lane * 16;
      int r = off >> 6, cb = (off & 63) >> 1;
      gld_lds16(A + (size_t)(m0 + r) * NH + k0 + cb, &As[r][cb]);
      gld_lds16(B + (size_t)(n0 + r) * NH + k0 + cb, &Bs[r][cb]);
    }
    __syncthreads();
    int r16 = lane & 15, kb = (lane >> 4) * 8;
    bf16x8 af[4], bfr[4];
#pragma unroll
    for (int i = 0; i < 4; ++i) {
      af[i]  = *(const bf16x8*)&As[wr * 64 + i * 16 + r16][kb];
      bfr[i] = *(const bf16x8*)&Bs[wc * 64 + i * 16 + r16][kb];
    }
#pragma unroll
    for (int i = 0; i < 4; ++i)
#pragma unroll
      for (int j = 0; j < 4; ++j)
        acc[i][j] = __builtin_amdgcn_mfma_f32_16x16x32_bf16(af[i], bfr[j], acc[i][j], 0, 0, 0);
  }
  int r16 = lane & 15, rg = lane >> 4;
#pragma unroll
  for (int i = 0; i < 4; ++i)
#pragma unroll
    for (int j = 0; j < 4; ++j) {
      int ccol = n0 + wc * 64 + j * 16 + r16;
#pragma unroll
      for (int q = 0; q < 4; ++q) {
        int crow = m0 + wr * 64 + i * 16 + rg * 4 + q;   // = b*64+s
        C[(size_t)crow * G3 + ccol] = __float2bfloat16(acc[i][j][q]);
      }
    }
}

// ---------------------------------------------------------------------------
// Attention prefix tables (gi(δ) collapse — see R12).
// ---------------------------------------------------------------------------
__global__ __launch_bounds__(256) void k_tabs(
    const __hip_bfloat16* __restrict__ ENCW, const float* __restrict__ escoreT,
    __hip_bfloat16* __restrict__ TP, __hip_bfloat16* __restrict__ TQ,
    float* __restrict__ thrG, float* __restrict__ sigG) {
  __shared__ float thrL[64];
  __shared__ int   idxL[64];
  __shared__ float wexpL[64];
  int b = blockIdx.x, t = threadIdx.x;
  if (t < 64) {   // rank-sort (desc, index tiebreak)
    float mine = escoreT[b * 64 + t];
    int rank = 0;
    for (int j = 0; j < 64; ++j) {
      float v = __shfl(mine, j, 64);
      rank += (v > mine) || (v == mine && j < t);
    }
    thrL[rank] = mine;
    idxL[rank] = t;
  }
  __syncthreads();
  if (t < 64) {
    float e = __expf(thrL[t]);
    wexpL[t] = e;
    float s = e;
    for (int off = 1; off < 64; off <<= 1) {
      float o = __shfl_up(s, off, 64);
      if (t >= off) s += o;
    }
    sigG[b * 65 + t + 1] = s;
    if (t == 0) sigG[b * 65] = 0.f;
    thrG[b * 64 + t] = thrL[t];
  }
  __syncthreads();
#pragma unroll
  for (int cc = 0; cc < 3; ++cc) {
    int c = t + cc * 256;
    const __hip_bfloat16* ep = ENCW + (size_t)b * 64 * G3 + c;
    float T = 0.f;
    for (int s = 0; s < 64; ++s) T += __bfloat162float(ep[(size_t)s * G3]);
    float P = 0.f, U = 0.f;
    __hip_bfloat16* tp = TP + (size_t)b * 65 * G3 + c;
    __hip_bfloat16* tq = TQ + (size_t)b * 65 * G3 + c;
    tp[0] = __float2bfloat16(0.f);
    tq[0] = __float2bfloat16(T);
    for (int m = 1; m <= 64; ++m) {
      int j = idxL[m - 1];
      float e = __bfloat162float(ep[(size_t)j * G3]);
      P += wexpL[m - 1] * e;
      U += e;
      tp[(size_t)m * G3] = __float2bfloat16(P);
      tq[(size_t)m * G3] = __float2bfloat16(T - U);
    }
  }
}

// ---------------------------------------------------------------------------
// Pre-gather decoder one-hot input term (bf16 out): Gdec = bih + onehot col.
// ---------------------------------------------------------------------------
__global__ __launch_bounds__(256) void k_pregather(
    const float* __restrict__ Wih, const float* __restrict__ bih,
    const int* __restrict__ gt, __hip_bfloat16* __restrict__ Gdec) {
  int ib = blockIdx.x;              // i*64+b
  int i = ib >> 6, b = ib & 63;
  int tok = (i > 0) ? gt[b * NL + (i - 1)] : -1;
  for (int g = threadIdx.x; g < G3; g += 256) {
    float v = bih[g];
    if (tok >= 0) v += Wih[(size_t)g * (NH + NVOUT) + NH + tok];
    Gdec[(size_t)ib * G3 + g] = __float2bfloat16(v);
  }
}

// ---------------------------------------------------------------------------
// Encoder scan v6: 16 WGs x 512 thr, FOUR batches/WG (A rows 0-3 = batches;
// rows 4-15 garbage — inert since C row r depends only on A row r). 48 MFMA
// per wave per step now serve 4 batches; gates use 4 acc elements/lane on
// lanes<16 (8 triples). r,z panels VGPR-resident; n panel L2-streamed
// (opaque-ptr vs LICM). Gi is bf16. Raw barriers.
// ---------------------------------------------------------------------------
__global__ __launch_bounds__(512) void k_encoder6(
    const __hip_bfloat16* __restrict__ Gi, const __hip_bfloat16* __restrict__ Wcat,
    const float* __restrict__ bhh, __hip_bfloat16* __restrict__ enchB) {
  __shared__ __hip_bfloat16 hbf[2][16][256];   // rows 0-3 live, 16KB
  int t = threadIdx.x, w = t >> 6, lane = t & 63;
  int b0 = blockIdx.x * 4;
  int r16 = lane & 15, hi16 = lane >> 4;
  int cw = w * 32;
  bf16x8 wv[2][2][8];                          // r,z panels resident
#pragma unroll
  for (int f = 0; f < 2; ++f)
#pragma unroll
    for (int fc = 0; fc < 2; ++fc)
#pragma unroll
      for (int kf = 0; kf < 8; ++kf)
        wv[f][fc][kf] = *(const bf16x8*)(Wcat +
            (((size_t)f * 256 + cw + fc * 16 + r16) * 256 + kf * 32 + hi16 * 8));
  float bh0[2], bh1[2], bh2[2];
#pragma unroll
  for (int fc = 0; fc < 2; ++fc) {
    bh0[fc] = bhh[cw + fc * 16 + r16];
    bh1[fc] = bhh[256 + cw + fc * 16 + r16];
    bh2[fc] = bhh[512 + cw + fc * 16 + r16];
  }
  // init: zero rows 0-3 of both buffers (2KB each)
  if (t < 512) {
    ((unsigned*)&hbf[0][0][0])[t] = 0u;
    ((unsigned*)&hbf[1][0][0])[t] = 0u;
  }
  __syncthreads();
  float hp[4][2] = {};
  unsigned long long wna = (unsigned long long)(Wcat + (size_t)2 * 65536);
  int cur = 0;
  for (int s = 0; s < NS; ++s) {
    asm volatile("" : "+v"(wna));
    const __hip_bfloat16* wnp = (const __hip_bfloat16*)wna;
    // Gi loads (bf16), lanes<16: 4 batches x 2fc x 3 gates
    unsigned short gg[4][2][3];
    if (hi16 == 0) {
#pragma unroll
      for (int q = 0; q < 4; ++q) {
        const unsigned short* gp = (const unsigned short*)
            (Gi + ((size_t)(b0 + q) * 64 + s) * G3);
#pragma unroll
        for (int fc = 0; fc < 2; ++fc) {
          int c = cw + fc * 16 + lane;
          gg[q][fc][0] = gp[c]; gg[q][fc][1] = gp[256 + c]; gg[q][fc][2] = gp[512 + c];
        }
      }
    }
    // A-frags: lane row = l&15 (batches 0-3 real), XOR-swizzled
    const char* hb = (const char*)&hbf[cur][0][0];
    bf16x8 ah[8];
#pragma unroll
    for (int kf = 0; kf < 8; ++kf)
      ah[kf] = *(const bf16x8*)(hb + r16 * 512 + (((kf * 64 + hi16 * 16)) ^ ((r16 & 7) << 4)));
    f32x4 acc[2][2] = {};
    f32x4 ghn[2] = {};
#pragma unroll
    for (int fc = 0; fc < 2; ++fc) {
      bf16x8 wn[8];
#pragma unroll
      for (int kf = 0; kf < 8; ++kf)
        wn[kf] = *(const bf16x8*)(wnp +
            ((size_t)(cw + fc * 16 + r16) * 256 + kf * 32 + hi16 * 8));
#pragma unroll
      for (int kf = 0; kf < 8; ++kf) {
        acc[0][fc] = __builtin_amdgcn_mfma_f32_16x16x32_bf16(ah[kf], wv[0][fc][kf], acc[0][fc], 0, 0, 0);
        acc[1][fc] = __builtin_amdgcn_mfma_f32_16x16x32_bf16(ah[kf], wv[1][fc][kf], acc[1][fc], 0, 0, 0);
        ghn[fc]    = __builtin_amdgcn_mfma_f32_16x16x32_bf16(ah[kf], wn[kf], ghn[fc], 0, 0, 0);
      }
    }
    if (hi16 == 0) {
      int nxt = cur ^ 1;
      char* hw = (char*)&hbf[nxt][0][0];
#pragma unroll
      for (int q = 0; q < 4; ++q)
#pragma unroll
        for (int fc = 0; fc < 2; ++fc) {
          int c = cw + fc * 16 + lane;
          float rr = 1.f / (1.f + __expf(-(bf2f(gg[q][fc][0]) + acc[0][fc][q] + bh0[fc])));
          float zz = 1.f / (1.f + __expf(-(bf2f(gg[q][fc][1]) + acc[1][fc][q] + bh1[fc])));
          float nn = fast_tanh(bf2f(gg[q][fc][2]) + rr * (ghn[fc][q] + bh2[fc]));
          float hn = (1.f - zz) * nn + zz * hp[q][fc];
          hp[q][fc] = hn;
          *(unsigned short*)(hw + q * 512 + ((2 * c) ^ (q << 4))) = (unsigned short)f2bf(hn);
          enchB[((size_t)(b0 + q) * 64 + s) * 256 + c] = __float2bfloat16(hn);
        }
    }
    lds_barrier();
    cur ^= 1;
  }
}

// escoreT[b*64+s] = enc_h[b][s] . w_enc
__global__ __launch_bounds__(256) void k_escoreB(
    const __hip_bfloat16* __restrict__ enchB, const float* __restrict__ att_w,
    float* __restrict__ escoreT) {
  int row = blockIdx.x * 4 + (threadIdx.x >> 6);   // = b*64+s
  int lane = threadIdx.x & 63;
  ushort4 u = *(const ushort4*)(enchB + (size_t)row * 256 + lane * 4);
  const float* we = att_w + 256 + lane * 4;
  float p = bf2f(u.x) * we[0] + bf2f(u.y) * we[1]
          + bf2f(u.z) * we[2] + bf2f(u.w) * we[3];
#pragma unroll
  for (int off = 32; off; off >>= 1) p += __shfl_xor(p, off, 64);
  if (lane == 0) escoreT[row] = p;
}

// ---------------------------------------------------------------------------
// Decoder scan v9: 16 WGs x 512 thr, FOUR batches/WG. gi via (TP,TQ,sig)
// tables per batch; delta via cross-barrier psum [8w][4q]; m via 4 ballots
// with per-lane thrq[4]. r,z Whh resident; n streamed. Raw barriers.
// ---------------------------------------------------------------------------
__global__ __launch_bounds__(512) void k_decoder9(
    const __hip_bfloat16* __restrict__ Gdec, const __hip_bfloat16* __restrict__ Wcat6,
    const float* __restrict__ bhh, const __hip_bfloat16* __restrict__ enchB,
    const __hip_bfloat16* __restrict__ TP, const __hip_bfloat16* __restrict__ TQ,
    const float* __restrict__ thrG, const float* __restrict__ sigG,
    const float* __restrict__ att_w, const float* __restrict__ att_b,
    __hip_bfloat16* __restrict__ dechb) {
  __shared__ __hip_bfloat16 hbf[2][16][256];   // rows 0-3 live
  __shared__ float psumL[2][8][4];
  __shared__ float sigL[4][65];
  int t = threadIdx.x, w = t >> 6, lane = t & 63;
  int b0 = blockIdx.x * 4;
  int r16 = lane & 15, hi16 = lane >> 4;
  int cw = w * 32;
  bf16x8 wv[2][2][8];                          // r,z panels (3,4) resident
#pragma unroll
  for (int f = 0; f < 2; ++f)
#pragma unroll
    for (int fc = 0; fc < 2; ++fc)
#pragma unroll
      for (int kf = 0; kf < 8; ++kf)
        wv[f][fc][kf] = *(const bf16x8*)(Wcat6 +
            (((size_t)(3 + f) * 256 + cw + fc * 16 + r16) * 256 + kf * 32 + hi16 * 8));
  float wd[2];
  wd[0] = att_w[cw + r16]; wd[1] = att_w[cw + 16 + r16];
  float attb = att_b[0];
  float thrq[4];
#pragma unroll
  for (int q = 0; q < 4; ++q) thrq[q] = thrG[(size_t)(b0 + q) * 64 + lane];
  if (t < 260) sigL[t / 65][t % 65] = sigG[(size_t)(b0 + t / 65) * 65 + t % 65];
  float bh0[2], bh1[2], bh2[2];
#pragma unroll
  for (int fc = 0; fc < 2; ++fc) {
    bh0[fc] = bhh[cw + fc * 16 + r16];
    bh1[fc] = bhh[256 + cw + fc * 16 + r16];
    bh2[fc] = bhh[512 + cw + fc * 16 + r16];
  }
  // init: h0 = enc h at s=63 (rows 0-3, swizzled)
  if (t < 1024) {
    int q = t >> 8, c = t & 255;
    unsigned short v = ((const unsigned short*)enchB)[((size_t)(b0 + q) * 64 + 63) * 256 + c];
    *(unsigned short*)((char*)&hbf[0][0][0] + q * 512 + ((2 * c) ^ (q << 4))) = v;
  }
  float hp[4][2];
  if (hi16 == 0) {
#pragma unroll
    for (int q = 0; q < 4; ++q) {
      const unsigned short* hq = (const unsigned short*)enchB + ((size_t)(b0 + q) * 64 + 63) * 256;
      hp[q][0] = bf2f(hq[cw + lane]);
      hp[q][1] = bf2f(hq[cw + 16 + lane]);
    }
    float pp[4];
#pragma unroll
    for (int q = 0; q < 4; ++q) pp[q] = hp[q][0] * wd[0] + hp[q][1] * wd[1];
#pragma unroll
    for (int off = 1; off < 16; off <<= 1)
#pragma unroll
      for (int q = 0; q < 4; ++q) pp[q] += __shfl_xor(pp[q], off, 64);
    if (lane == 0) { float4 v4 = {pp[0], pp[1], pp[2], pp[3]}; *(float4*)&psumL[0][w][0] = v4; }
  }
  __syncthreads();
  unsigned long long wna = (unsigned long long)(Wcat6 + (size_t)5 * 65536);
  int cur = 0;
  for (int i = 0; i < NL; ++i) {
    asm volatile("" : "+v"(wna));
    const __hip_bfloat16* wnp = (const __hip_bfloat16*)wna;
    // Gdec loads (bf16, HBM-cold) issued first
    unsigned short gg[4][2][3];
    if (hi16 == 0) {
#pragma unroll
      for (int q = 0; q < 4; ++q) {
        const unsigned short* gp = (const unsigned short*)
            (Gdec + ((size_t)i * 64 + b0 + q) * G3);
#pragma unroll
        for (int fc = 0; fc < 2; ++fc) {
          int c = cw + fc * 16 + lane;
          gg[q][fc][0] = gp[c]; gg[q][fc][1] = gp[256 + c]; gg[q][fc][2] = gp[512 + c];
        }
      }
    }
    // delta per batch from psum (broadcast LDS reads, all lanes)
    float dq[4] = {};
#pragma unroll
    for (int wq = 0; wq < 8; ++wq) {
      float4 v4 = *(const float4*)&psumL[cur][wq][0];
      dq[0] += v4.x; dq[1] += v4.y; dq[2] += v4.z; dq[3] += v4.w;
    }
    float ed[4]; int m[4];
#pragma unroll
    for (int q = 0; q < 4; ++q) {
      dq[q] += attb;
      ed[q] = __expf(dq[q]);
      m[q] = __popcll(__ballot(thrq[q] + dq[q] > 0.f));
    }
    // table loads (L2), lanes<16 — issued before the MFMA block
    unsigned short tpv[4][2][3], tqv[4][2][3];
    float sg[4];
    if (hi16 == 0) {
#pragma unroll
      for (int q = 0; q < 4; ++q) {
        const unsigned short* tpr = (const unsigned short*)TP + ((size_t)(b0 + q) * 65 + m[q]) * G3;
        const unsigned short* tqr = (const unsigned short*)TQ + ((size_t)(b0 + q) * 65 + m[q]) * G3;
        sg[q] = sigL[q][m[q]];
#pragma unroll
        for (int fc = 0; fc < 2; ++fc) {
          int c = cw + fc * 16 + lane;
          tpv[q][fc][0] = tpr[c]; tpv[q][fc][1] = tpr[256 + c]; tpv[q][fc][2] = tpr[512 + c];
          tqv[q][fc][0] = tqr[c]; tqv[q][fc][1] = tqr[256 + c]; tqv[q][fc][2] = tqr[512 + c];
        }
      }
    }
    // gh MFMAs (A rows = batches)
    const char* hb = (const char*)&hbf[cur][0][0];
    bf16x8 ah[8];
#pragma unroll
    for (int kf = 0; kf < 8; ++kf)
      ah[kf] = *(const bf16x8*)(hb + r16 * 512 + (((kf * 64 + hi16 * 16)) ^ ((r16 & 7) << 4)));
    f32x4 acch[2][2] = {};
    f32x4 ghn[2] = {};
#pragma unroll
    for (int fc = 0; fc < 2; ++fc) {
      bf16x8 wn[8];
#pragma unroll
      for (int kf = 0; kf < 8; ++kf)
        wn[kf] = *(const bf16x8*)(wnp +
            ((size_t)(cw + fc * 16 + r16) * 256 + kf * 32 + hi16 * 8));
#pragma unroll
      for (int kf = 0; kf < 8; ++kf) {
        acch[0][fc] = __builtin_amdgcn_mfma_f32_16x16x32_bf16(ah[kf], wv[0][fc][kf], acch[0][fc], 0, 0, 0);
        acch[1][fc] = __builtin_amdgcn_mfma_f32_16x16x32_bf16(ah[kf], wv[1][fc][kf], acch[1][fc], 0, 0, 0);
        ghn[fc]     = __builtin_amdgcn_mfma_f32_16x16x32_bf16(ah[kf], wn[kf], ghn[fc], 0, 0, 0);
      }
    }
    // gates + h update + next psum partial (lanes<16)
    if (hi16 == 0) {
      int nxt = cur ^ 1;
      char* hw = (char*)&hbf[nxt][0][0];
      float rn[4];
#pragma unroll
      for (int q = 0; q < 4; ++q) rn[q] = 1.f / (ed[q] * sg[q] + (float)(64 - m[q]));
      float pp[4];
#pragma unroll
      for (int q = 0; q < 4; ++q) {
        float hnf[2];
#pragma unroll
        for (int fc = 0; fc < 2; ++fc) {
          int c = cw + fc * 16 + lane;
          float gir = (ed[q] * bf2f(tpv[q][fc][0]) + bf2f(tqv[q][fc][0])) * rn[q];
          float giz = (ed[q] * bf2f(tpv[q][fc][1]) + bf2f(tqv[q][fc][1])) * rn[q];
          float gin = (ed[q] * bf2f(tpv[q][fc][2]) + bf2f(tqv[q][fc][2])) * rn[q];
          float rr = 1.f / (1.f + __expf(-(bf2f(gg[q][fc][0]) + gir + acch[0][fc][q] + bh0[fc])));
          float zz = 1.f / (1.f + __expf(-(bf2f(gg[q][fc][1]) + giz + acch[1][fc][q] + bh1[fc])));
          float nn = fast_tanh(bf2f(gg[q][fc][2]) + gin + rr * (ghn[fc][q] + bh2[fc]));
          float hn = (1.f - zz) * nn + zz * hp[q][fc];
          hp[q][fc] = hn; hnf[fc] = hn;
          *(unsigned short*)(hw + q * 512 + ((2 * c) ^ (q << 4))) = (unsigned short)f2bf(hn);
          int cs = (c & ~63) | ((c & 63) ^ (((b0 + q) & 7) << 3));
          dechb[((size_t)i * 64 + b0 + q) * 256 + cs] = __float2bfloat16(hn);
        }
        pp[q] = hnf[0] * wd[0] + hnf[1] * wd[1];
      }
#pragma unroll
      for (int off = 1; off < 16; off <<= 1)
#pragma unroll
        for (int q = 0; q < 4; ++q) pp[q] += __shfl_xor(pp[q], off, 64);
      if (lane == 0) { float4 v4 = {pp[0], pp[1], pp[2], pp[3]}; *(float4*)&psumL[cur ^ 1][w][0] = v4; }
    }
    lds_barrier();
    cur ^= 1;
  }
}

// ---------------------------------------------------------------------------
// Log-softmax, register-resident single read + single write (one WG/row).
// ---------------------------------------------------------------------------
__global__ __launch_bounds__(256) void k_logsoftmax(float* __restrict__ out) {
  float* x = out + (size_t)blockIdx.x * NVOUT;
  __shared__ float red[256];
  int t = threadIdx.x;
  float4 v[10];
  float mx = -1e30f;
#pragma unroll
  for (int ii = 0; ii < 10; ++ii) {
    int slot = ii * 256 + t;
    if (slot < 2500) {
      v[ii] = *(const float4*)(x + slot * 4);
      mx = fmaxf(mx, fmaxf(fmaxf(v[ii].x, v[ii].y), fmaxf(v[ii].z, v[ii].w)));
    }
  }
  red[t] = mx; __syncthreads();
  for (int off = 128; off; off >>= 1) {
    if (t < off) red[t] = fmaxf(red[t], red[t + off]);
    __syncthreads();
  }
  mx = red[0]; __syncthreads();
  float sm = 0.f;
#pragma unroll
  for (int ii = 0; ii < 10; ++ii) {
    int slot = ii * 256 + t;
    if (slot < 2500)
      sm += __expf(v[ii].x - mx) + __expf(v[ii].y - mx)
          + __expf(v[ii].z - mx) + __expf(v[ii].w - mx);
  }
  red[t] = sm; __syncthreads();
  for (int off = 128; off; off >>= 1) {
    if (t < off) red[t] += red[t + off];
    __syncthreads();
  }
  float lse = mx + logf(red[0]);
#pragma unroll
  for (int ii = 0; ii < 10; ++ii) {
    int slot = ii * 256 + t;
    if (slot < 2500) {
      float4 o; o.x = v[ii].x - lse; o.y = v[ii].y - lse;
      o.z = v[ii].z - lse; o.w = v[ii].w - lse;
      *(float4*)(x + slot * 4) = o;
    }
  }
}

// ---------------------------------------------------------------------------
extern "C" void kernel_launch(void* const* d_in, const int* in_sizes, int n_in,
                              void* d_out, int out_size, void* d_ws, size_t ws_size,
                              hipStream_t stream) {
  const float* X        = (const float*)d_in[0];
  const int*   gt       = (const int*)  d_in[1];
  const float* enc_Wih  = (const float*)d_in[2];
  const float* enc_Whh  = (const float*)d_in[3];
  const float* enc_bih  = (const float*)d_in[4];
  const float* enc_bhh  = (const float*)d_in[5];
  const float* att_w    = (const float*)d_in[6];
  const float* att_b    = (const float*)d_in[7];
  const float* dec_Wih  = (const float*)d_in[8];
  const float* dec_Whh  = (const float*)d_in[9];
  const float* dec_bih  = (const float*)d_in[10];
  const float* dec_bhh  = (const float*)d_in[11];
  const float* out_W    = (const float*)d_in[12];
  const float* out_b    = (const float*)d_in[13];
  float* out = (float*)d_out;

  // workspace carve-up
  float* p = (float*)d_ws;
  float* Gienc  = p; p += NS * NB * G3;          // slot sized fp32; holds bf16 now
  float* Gdec   = p; p += NL * NB * G3;          // slot sized fp32; holds bf16 now
  float* escoreT = p; p += NB * NS;
  __hip_bfloat16* q = (__hip_bfloat16*)p;
  __hip_bfloat16* enchBb = q; q += (size_t)NB * NS * NH;
  __hip_bfloat16* Wcat_e = q; q += (size_t)3 * 256 * 256;
  __hip_bfloat16* Wcat_d = q; q += (size_t)6 * 256 * 256;
  __hip_bfloat16* Xb     = q; q += (size_t)4096 * KP2;
  __hip_bfloat16* Wencb  = q; q += (size_t)G3 * KP2;
  __hip_bfloat16* Woutb  = q; q += (size_t)NOUTP * NH;
  __hip_bfloat16* dechb  = q; q += (size_t)NL * NB * NH;
  __hip_bfloat16* Gienc_b = (__hip_bfloat16*)Gienc;   // bf16 [4096][768]
  __hip_bfloat16* Gdec_b  = (__hip_bfloat16*)Gdec;    // bf16 [4096][768]
  // ENCW aliases the tail of the Gienc slot region? -> ENCW aliases Gienc base
  __hip_bfloat16* ENCW   = (__hip_bfloat16*)Gienc + (size_t)4096 * G3;  // second half of 12.6MB slot
  // attention tables alias Xb (dead after k_gemm_encS)
  __hip_bfloat16* TP  = Xb;                               // 6.4 MB
  __hip_bfloat16* TQ  = Xb + (size_t)64 * 65 * G3;        // 6.4 MB
  float* thrG = (float*)(Xb + (size_t)2 * 64 * 65 * G3);
  float* sigG = thrG + 64 * 64;
  // split-K partials (50 MB fp32) in d_out scratch (overwritten later)
  float* Pout = (float*)d_out;

  // prep (independent)
  k_cvt_pad<<<4096, 256, 0, stream>>>(X, Xb, 4096, NVIN, KP2, 1);
  k_cvt_pad<<<G3, 256, 0, stream>>>(enc_Wih, Wencb, G3, NVIN, KP2, 1);
  k_cvt_pad<<<NOUTP, 256, 0, stream>>>(out_W, Woutb, NVOUT, NH, NH, 1);
  k_wpack<<<768, 256, 0, stream>>>(enc_Whh, NH, enc_Whh, NH, Wcat_e, 3 * 65536);
  k_wpack<<<1536, 256, 0, stream>>>(dec_Wih, NH + NVOUT, dec_Whh, NH, Wcat_d, 6 * 65536);
  k_pregather<<<NL * NB, 256, 0, stream>>>(dec_Wih, dec_bih, gt, Gdec_b);

  k_gemm_encS<<<dim3(6, 32, 4), 256, 0, stream>>>(Xb, Wencb, Pout);
  k_reduce4<<<3072, 256, 0, stream>>>((const float4*)Pout, enc_bih, (ushort4*)Gienc_b);
  k_encoder6<<<16, 512, 0, stream>>>(Gienc_b, Wcat_e, enc_bhh, enchBb);
  k_escoreB<<<1024, 256, 0, stream>>>(enchBb, att_w, escoreT);
  k_gemm_encw<<<dim3(6, 32), 256, 0, stream>>>(enchBb, Wcat_d, ENCW);
  k_tabs<<<64, 256, 0, stream>>>(ENCW, escoreT, TP, TQ, thrG, sigG);
  k_decoder9<<<16, 512, 0, stream>>>(Gdec_b, Wcat_d, dec_bhh, enchBb, TP, TQ,
                                     thrG, sigG, att_w, att_b, dechb);
  k_gemm_outS<<<dim3(79, 32), 256, 0, stream>>>(dechb, Woutb, out_b, out);
  k_logsoftmax<<<NB * NL, 256, 0, stream>>>(out);
}

// Round 14
// 778.515 us; speedup vs baseline: 1.9239x; 1.9239x over previous
//
#include <hip/hip_runtime.h>
#include <hip/hip_bf16.h>
#include <math.h>

// Problem dims (fixed by the reference)
#define NB 64      // batch
#define NS 64      // encoder steps
#define NL 64      // decoder steps
#define NH 256     // hidden
#define G3 768     // 3*NH (gates r,z,n)
#define NVIN 10000
#define NVOUT 10000
#define KP2 10240   // NVIN padded (4 splits x 40 x BK=64)
#define NOUTP 10112 // NVOUT padded to 128 for out GEMM

typedef __attribute__((ext_vector_type(8))) short bf16x8;  // 8 bf16 (4 VGPRs)
typedef __attribute__((ext_vector_type(4))) float f32x4;   // MFMA accumulator
typedef __attribute__((ext_vector_type(4))) unsigned int u32x4;

// async global->LDS, 16B per lane (dest must be wave-uniform base + lane*16)
__device__ __forceinline__ void gld_lds16(const __hip_bfloat16* g, __hip_bfloat16* l) {
  __builtin_amdgcn_global_load_lds(
      (const __attribute__((address_space(1))) unsigned int*)(const void*)g,
      (__attribute__((address_space(3))) unsigned int*)(void*)l, 16, 0, 0);
}

__device__ __forceinline__ unsigned int f2bf(float f) {  // RNE fp32->bf16 bits
  unsigned int u = __float_as_uint(f);
  return (u + 0x7fff + ((u >> 16) & 1)) >> 16;
}
__device__ __forceinline__ float fast_tanh(float x) {   // tanh via v_exp_f32
  float e = __expf(-2.f * x);
  return (1.f - e) / (1.f + e);
}
// Workgroup barrier WITHOUT the vmcnt(0) drain __syncthreads() emits.
__device__ __forceinline__ void lds_barrier() {
  asm volatile("s_waitcnt lgkmcnt(0)\n\ts_barrier" ::: "memory");
}

// ---------------------------------------------------------------------------
// fp32 -> bf16 convert with padding; swz=1 pre-swizzles columns within each
// 64-group by ((row&7)<<3) (T2/m173: swizzle SOURCE, LDS dest linear).
// ---------------------------------------------------------------------------
__global__ __launch_bounds__(256) void k_cvt_pad(
    const float* __restrict__ in, __hip_bfloat16* __restrict__ out,
    int in_rows, int in_cols, int out_cols, int swz) {
  int r = blockIdx.x;
  const float* src = in + (size_t)r * in_cols;
  __hip_bfloat16* dst = out + (size_t)r * out_cols;
  bool live = r < in_rows;
  int sx = swz ? ((r & 7) << 3) : 0;
  for (int c = threadIdx.x * 4; c < out_cols; c += 1024) {
    int cc = (c & ~63) | ((c & 63) ^ sx);
    __hip_bfloat16 v[4];
    if (live && cc + 3 < in_cols) {
      float4 f = *(const float4*)(src + cc);
      v[0] = __float2bfloat16(f.x); v[1] = __float2bfloat16(f.y);
      v[2] = __float2bfloat16(f.z); v[3] = __float2bfloat16(f.w);
    } else {
      v[0] = v[1] = v[2] = v[3] = __float2bfloat16(0.f);
    }
    *(ushort4*)(dst + c) = *(const ushort4*)v;
  }
}

// ---------------------------------------------------------------------------
// Pack recurrent weights to bf16 Wcat[f][c][k].
// ---------------------------------------------------------------------------
__global__ __launch_bounds__(256) void k_wpack(
    const float* __restrict__ srcA, int strideA,
    const float* __restrict__ srcB, int strideB,
    __hip_bfloat16* __restrict__ out, int total) {
  int idx = blockIdx.x * 256 + threadIdx.x;
  if (idx >= total) return;
  int k = idx & 255, c = (idx >> 8) & 255, f = idx >> 16;
  float v = (f < 3) ? srcA[(size_t)(f * 256 + c) * strideA + k]
                    : srcB[(size_t)((f - 3) * 256 + c) * strideB + k];
  out[idx] = __float2bfloat16(v);
}

// ---------------------------------------------------------------------------
// Enc GEMM, split-K (see R7): P[z] partials, reduced by k_reduce4.
// ---------------------------------------------------------------------------
__global__ __launch_bounds__(256) void k_gemm_encS(
    const __hip_bfloat16* __restrict__ A, const __hip_bfloat16* __restrict__ B,
    float* __restrict__ P) {
  __shared__ __hip_bfloat16 As[128][64];
  __shared__ __hip_bfloat16 Bs[128][64];
  int t = threadIdx.x;
  int wid = t >> 6, lane = t & 63;
  int m0 = blockIdx.y * 128, n0 = blockIdx.x * 128;
  int wr = wid >> 1, wc = wid & 1;
  int r16 = lane & 15, hi16 = lane >> 4;
  int xr = (r16 & 7) << 4;
  f32x4 acc[4][4] = {};
  int kbeg = blockIdx.z * 2560;
  for (int ks = 0; ks < 40; ++ks) {
    int k0 = kbeg + ks * 64;
    __syncthreads();
#pragma unroll
    for (int is = 0; is < 4; ++is) {
      int off = is * 4096 + t * 16;
      int r = off >> 7, e = (off & 127) >> 1;
      gld_lds16(A + (size_t)(m0 + r) * KP2 + k0 + e, &As[r][e]);
      gld_lds16(B + (size_t)(n0 + r) * KP2 + k0 + e, &Bs[r][e]);
    }
    __syncthreads();
    const char* ab = (const char*)As;
    const char* bb = (const char*)Bs;
#pragma unroll
    for (int kk = 0; kk < 2; ++kk) {
      int ko = kk * 64 + hi16 * 16;
      bf16x8 af[4], bfr[4];
#pragma unroll
      for (int i = 0; i < 4; ++i) {
        af[i]  = *(const bf16x8*)(ab + (wr * 64 + i * 16 + r16) * 128 + (ko ^ xr));
        bfr[i] = *(const bf16x8*)(bb + (wc * 64 + i * 16 + r16) * 128 + (ko ^ xr));
      }
#pragma unroll
      for (int i = 0; i < 4; ++i)
#pragma unroll
        for (int j = 0; j < 4; ++j)
          acc[i][j] = __builtin_amdgcn_mfma_f32_16x16x32_bf16(af[i], bfr[j], acc[i][j], 0, 0, 0);
    }
  }
  float* Pz = P + (size_t)blockIdx.z * 4096 * G3;
#pragma unroll
  for (int i = 0; i < 4; ++i)
#pragma unroll
    for (int j = 0; j < 4; ++j) {
      int ccol = n0 + wc * 64 + j * 16 + r16;
#pragma unroll
      for (int q = 0; q < 4; ++q) {
        int crow = m0 + wr * 64 + i * 16 + hi16 * 4 + q;
        Pz[(size_t)crow * G3 + ccol] = acc[i][j][q];
      }
    }
}

// Gienc = P0+P1+P2+P3 + bias  (fp32 — R13's bf16 ate the absmax margin)
__global__ __launch_bounds__(256) void k_reduce4(
    const float4* __restrict__ P, const float* __restrict__ bias,
    float4* __restrict__ G) {
  int idx = blockIdx.x * 256 + threadIdx.x;
  float4 a = P[idx], b = P[idx + 786432], c = P[idx + 2 * 786432],
         d = P[idx + 3 * 786432];
  float4 bs = *(const float4*)(bias + (idx % 192) * 4);
  float4 o;
  o.x = a.x + b.x + c.x + d.x + bs.x;
  o.y = a.y + b.y + c.y + d.y + bs.y;
  o.z = a.z + b.z + c.z + d.z + bs.z;
  o.w = a.w + b.w + c.w + d.w + bs.w;
  G[idx] = o;
}

// ---------------------------------------------------------------------------
// Out GEMM (BK=64 + swizzle, see R7).
// ---------------------------------------------------------------------------
__global__ __launch_bounds__(256) void k_gemm_outS(
    const __hip_bfloat16* __restrict__ A, const __hip_bfloat16* __restrict__ B,
    const float* __restrict__ bias, float* __restrict__ C) {
  __shared__ __hip_bfloat16 As[128][64];
  __shared__ __hip_bfloat16 Bs[128][64];
  int t = threadIdx.x;
  int wid = t >> 6, lane = t & 63;
  int m0 = blockIdx.y * 128, n0 = blockIdx.x * 128;
  int wr = wid >> 1, wc = wid & 1;
  int r16 = lane & 15, hi16 = lane >> 4;
  int xr = (r16 & 7) << 4;
  f32x4 acc[4][4] = {};
  for (int k0 = 0; k0 < NH; k0 += 64) {
    __syncthreads();
#pragma unroll
    for (int is = 0; is < 4; ++is) {
      int off = is * 4096 + t * 16;
      int r = off >> 7, e = (off & 127) >> 1;
      gld_lds16(A + (size_t)(m0 + r) * NH + k0 + e, &As[r][e]);
      gld_lds16(B + (size_t)(n0 + r) * NH + k0 + e, &Bs[r][e]);
    }
    __syncthreads();
    const char* ab = (const char*)As;
    const char* bb = (const char*)Bs;
#pragma unroll
    for (int kk = 0; kk < 2; ++kk) {
      int ko = kk * 64 + hi16 * 16;
      bf16x8 af[4], bfr[4];
#pragma unroll
      for (int i = 0; i < 4; ++i) {
        af[i]  = *(const bf16x8*)(ab + (wr * 64 + i * 16 + r16) * 128 + (ko ^ xr));
        bfr[i] = *(const bf16x8*)(bb + (wc * 64 + i * 16 + r16) * 128 + (ko ^ xr));
      }
#pragma unroll
      for (int i = 0; i < 4; ++i)
#pragma unroll
        for (int j = 0; j < 4; ++j)
          acc[i][j] = __builtin_amdgcn_mfma_f32_16x16x32_bf16(af[i], bfr[j], acc[i][j], 0, 0, 0);
    }
  }
#pragma unroll
  for (int i = 0; i < 4; ++i)
#pragma unroll
    for (int j = 0; j < 4; ++j) {
      int ccol = n0 + wc * 64 + j * 16 + r16;
      if (ccol < NVOUT) {
        float bs = bias[ccol];
#pragma unroll
        for (int q = 0; q < 4; ++q) {
          int crow = m0 + wr * 64 + i * 16 + hi16 * 4 + q;  // = l*64+b
          int l = crow >> 6, b = crow & 63;
          C[((size_t)b * NL + l) * NVOUT + ccol] = acc[i][j][q] + bs;
        }
      }
    }
}

// ---------------------------------------------------------------------------
// ENCW GEMM (plain rows): ENCW[b*64+s][c] = sum_k ench[b*64+s][k]*Wih_ctx[c][k]
// ---------------------------------------------------------------------------
__global__ __launch_bounds__(256) void k_gemm_encw(
    const __hip_bfloat16* __restrict__ A, const __hip_bfloat16* __restrict__ B,
    __hip_bfloat16* __restrict__ C) {
  __shared__ __hip_bfloat16 As[128][32];
  __shared__ __hip_bfloat16 Bs[128][32];
  int t = threadIdx.x;
  int wid = t >> 6, lane = t & 63;
  int m0 = blockIdx.y * 128, n0 = blockIdx.x * 128;
  int wr = wid >> 1, wc = wid & 1;
  f32x4 acc[4][4] = {};
  for (int k0 = 0; k0 < NH; k0 += 32) {
    __syncthreads();
#pragma unroll
    for (int is = 0; is < 2; ++is) {
      int off = is * 4096 + wid * 1024 + lane * 16;
      int r = off >> 6, cb = (off & 63) >> 1;
      gld_lds16(A + (size_t)(m0 + r) * NH + k0 + cb, &As[r][cb]);
      gld_lds16(B + (size_t)(n0 + r) * NH + k0 + cb, &Bs[r][cb]);
    }
    __syncthreads();
    int r16 = lane & 15, kb = (lane >> 4) * 8;
    bf16x8 af[4], bfr[4];
#pragma unroll
    for (int i = 0; i < 4; ++i) {
      af[i]  = *(const bf16x8*)&As[wr * 64 + i * 16 + r16][kb];
      bfr[i] = *(const bf16x8*)&Bs[wc * 64 + i * 16 + r16][kb];
    }
#pragma unroll
    for (int i = 0; i < 4; ++i)
#pragma unroll
      for (int j = 0; j < 4; ++j)
        acc[i][j] = __builtin_amdgcn_mfma_f32_16x16x32_bf16(af[i], bfr[j], acc[i][j], 0, 0, 0);
  }
  int r16 = lane & 15, rg = lane >> 4;
#pragma unroll
  for (int i = 0; i < 4; ++i)
#pragma unroll
    for (int j = 0; j < 4; ++j) {
      int ccol = n0 + wc * 64 + j * 16 + r16;
#pragma unroll
      for (int q = 0; q < 4; ++q) {
        int crow = m0 + wr * 64 + i * 16 + rg * 4 + q;   // = b*64+s
        C[(size_t)crow * G3 + ccol] = __float2bfloat16(acc[i][j][q]);
      }
    }
}

// ---------------------------------------------------------------------------
// Attention prefix tables (gi(δ) collapse — see R12).
// ---------------------------------------------------------------------------
__global__ __launch_bounds__(256) void k_tabs(
    const __hip_bfloat16* __restrict__ ENCW, const float* __restrict__ escoreT,
    __hip_bfloat16* __restrict__ TP, __hip_bfloat16* __restrict__ TQ,
    float* __restrict__ thrG, float* __restrict__ sigG) {
  __shared__ float thrL[64];
  __shared__ int   idxL[64];
  __shared__ float wexpL[64];
  int b = blockIdx.x, t = threadIdx.x;
  if (t < 64) {   // rank-sort (desc, index tiebreak)
    float mine = escoreT[b * 64 + t];
    int rank = 0;
    for (int j = 0; j < 64; ++j) {
      float v = __shfl(mine, j, 64);
      rank += (v > mine) || (v == mine && j < t);
    }
    thrL[rank] = mine;
    idxL[rank] = t;
  }
  __syncthreads();
  if (t < 64) {
    float e = __expf(thrL[t]);
    wexpL[t] = e;
    float s = e;
    for (int off = 1; off < 64; off <<= 1) {
      float o = __shfl_up(s, off, 64);
      if (t >= off) s += o;
    }
    sigG[b * 65 + t + 1] = s;
    if (t == 0) sigG[b * 65] = 0.f;
    thrG[b * 64 + t] = thrL[t];
  }
  __syncthreads();
#pragma unroll
  for (int cc = 0; cc < 3; ++cc) {
    int c = t + cc * 256;
    const __hip_bfloat16* ep = ENCW + (size_t)b * 64 * G3 + c;
    float T = 0.f;
    for (int s = 0; s < 64; ++s) T += __bfloat162float(ep[(size_t)s * G3]);
    float P = 0.f, U = 0.f;
    __hip_bfloat16* tp = TP + (size_t)b * 65 * G3 + c;
    __hip_bfloat16* tq = TQ + (size_t)b * 65 * G3 + c;
    tp[0] = __float2bfloat16(0.f);
    tq[0] = __float2bfloat16(T);
    for (int m = 1; m <= 64; ++m) {
      int j = idxL[m - 1];
      float e = __bfloat162float(ep[(size_t)j * G3]);
      P += wexpL[m - 1] * e;
      U += e;
      tp[(size_t)m * G3] = __float2bfloat16(P);
      tq[(size_t)m * G3] = __float2bfloat16(T - U);
    }
  }
}

// ---------------------------------------------------------------------------
// Pre-gather decoder one-hot input term (fp32): Gdec = bih + onehot column.
// ---------------------------------------------------------------------------
__global__ __launch_bounds__(256) void k_pregather(
    const float* __restrict__ Wih, const float* __restrict__ bih,
    const int* __restrict__ gt, float* __restrict__ Gdec) {
  int ib = blockIdx.x;              // i*64+b
  int i = ib >> 6, b = ib & 63;
  int tok = (i > 0) ? gt[b * NL + (i - 1)] : -1;
  for (int g = threadIdx.x; g < G3; g += 256) {
    float v = bih[g];
    if (tok >= 0) v += Wih[(size_t)g * (NH + NVOUT) + NH + tok];
    Gdec[(size_t)ib * G3 + g] = v;
  }
}

// ---------------------------------------------------------------------------
// Encoder scan v5 (R11/R12 known-good): 64 WGs x 512 thr, one batch/WG.
// ---------------------------------------------------------------------------
__global__ __launch_bounds__(512) void k_encoder5(
    const float* __restrict__ Gi, const __hip_bfloat16* __restrict__ Wcat,
    const float* __restrict__ bhh, __hip_bfloat16* __restrict__ enchB) {
  __shared__ __hip_bfloat16 hbf[2][256];
  int t = threadIdx.x, w = t >> 6, lane = t & 63;
  int b = blockIdx.x;
  int r16 = lane & 15, hi16 = lane >> 4;
  int cw = w * 32;
  bf16x8 wv[3][2][8];
#pragma unroll
  for (int f = 0; f < 3; ++f)
#pragma unroll
    for (int fc = 0; fc < 2; ++fc)
#pragma unroll
      for (int kf = 0; kf < 8; ++kf)
        wv[f][fc][kf] = *(const bf16x8*)(Wcat +
            (((size_t)f * 256 + cw + fc * 16 + r16) * 256 + kf * 32 + hi16 * 8));
  float bh0[2], bh1[2], bh2[2];
#pragma unroll
  for (int fc = 0; fc < 2; ++fc) {
    bh0[fc] = bhh[cw + fc * 16 + r16];
    bh1[fc] = bhh[256 + cw + fc * 16 + r16];
    bh2[fc] = bhh[512 + cw + fc * 16 + r16];
  }
  if (t < 256) {
    hbf[0][t] = __float2bfloat16(0.f);
    hbf[1][t] = __float2bfloat16(0.f);
  }
  __syncthreads();
  float hp[2] = {0.f, 0.f};
  int cur = 0;
  for (int s = 0; s < NS; ++s) {
    float gd0[2], gd1[2], gd2[2];
    if (hi16 == 0) {
      const float* gp = Gi + ((size_t)b * 64 + s) * G3;
#pragma unroll
      for (int fc = 0; fc < 2; ++fc) {
        gd0[fc] = gp[cw + fc * 16 + r16];
        gd1[fc] = gp[256 + cw + fc * 16 + r16];
        gd2[fc] = gp[512 + cw + fc * 16 + r16];
      }
    }
    const char* hb = (const char*)&hbf[cur][0];
    f32x4 acc[3][2] = {};
#pragma unroll
    for (int half = 0; half < 2; ++half) {
      bf16x8 ah[4];
#pragma unroll
      for (int kf = 0; kf < 4; ++kf)
        ah[kf] = *(const bf16x8*)(hb + (half * 4 + kf) * 64 + hi16 * 16);  // broadcast
#pragma unroll
      for (int f = 0; f < 3; ++f)
#pragma unroll
        for (int fc = 0; fc < 2; ++fc)
#pragma unroll
          for (int kf = 0; kf < 4; ++kf)
            acc[f][fc] = __builtin_amdgcn_mfma_f32_16x16x32_bf16(
                ah[kf], wv[f][fc][half * 4 + kf], acc[f][fc], 0, 0, 0);
    }
    if (hi16 == 0) {
      int nxt = cur ^ 1;
#pragma unroll
      for (int fc = 0; fc < 2; ++fc) {
        int c = cw + fc * 16 + r16;
        float rr = 1.f / (1.f + __expf(-(gd0[fc] + acc[0][fc][0] + bh0[fc])));
        float zz = 1.f / (1.f + __expf(-(gd1[fc] + acc[1][fc][0] + bh1[fc])));
        float nn = fast_tanh(gd2[fc] + rr * (acc[2][fc][0] + bh2[fc]));
        float hn = (1.f - zz) * nn + zz * hp[fc];
        hp[fc] = hn;
        hbf[nxt][c] = __float2bfloat16(hn);
        enchB[((size_t)b * 64 + s) * 256 + c] = __float2bfloat16(hn);
      }
    }
    lds_barrier();
    cur ^= 1;
  }
}

// escoreT[b*64+s] = enc_h[b][s] . w_enc
__global__ __launch_bounds__(256) void k_escoreB(
    const __hip_bfloat16* __restrict__ enchB, const float* __restrict__ att_w,
    float* __restrict__ escoreT) {
  int row = blockIdx.x * 4 + (threadIdx.x >> 6);   // = b*64+s
  int lane = threadIdx.x & 63;
  ushort4 u = *(const ushort4*)(enchB + (size_t)row * 256 + lane * 4);
  const float* we = att_w + 256 + lane * 4;
  float p = __uint_as_float((unsigned)u.x << 16) * we[0]
          + __uint_as_float((unsigned)u.y << 16) * we[1]
          + __uint_as_float((unsigned)u.z << 16) * we[2]
          + __uint_as_float((unsigned)u.w << 16) * we[3];
#pragma unroll
  for (int off = 32; off; off >>= 1) p += __shfl_xor(p, off, 64);
  if (lane == 0) escoreT[row] = p;
}

// ---------------------------------------------------------------------------
// Decoder scan v8b (R12 structure + dead-load removal + early table loads):
// 64 WGs x 512 thr, 1 batch/WG, raw barriers, gi via (TP,TQ,sig) tables.
// Per step: psum -> delta -> ballot -> m -> 12 live table loads issued EARLY
// (latency hides under gh MFMAs) -> gh MFMAs -> gates -> h -> pipelined p.
// ---------------------------------------------------------------------------
__global__ __launch_bounds__(512) void k_decoder8(
    const float* __restrict__ Gdec, const __hip_bfloat16* __restrict__ Wcat6,
    const float* __restrict__ bhh, const __hip_bfloat16* __restrict__ enchB,
    const __hip_bfloat16* __restrict__ TP, const __hip_bfloat16* __restrict__ TQ,
    const float* __restrict__ thrG, const float* __restrict__ sigG,
    const float* __restrict__ att_w, const float* __restrict__ att_b,
    __hip_bfloat16* __restrict__ dechb) {
  __shared__ __hip_bfloat16 hbf[2][256];
  __shared__ float psumL[2][8];
  __shared__ float sigL[65];
  int t = threadIdx.x, w = t >> 6, lane = t & 63;
  int b = blockIdx.x;
  int r16 = lane & 15, hi16 = lane >> 4;
  int cw = w * 32;
  // all 3 Whh panels resident (panels 3,4,5 of Wcat6)
  bf16x8 wv[3][2][8];
#pragma unroll
  for (int f = 0; f < 3; ++f)
#pragma unroll
    for (int fc = 0; fc < 2; ++fc)
#pragma unroll
      for (int kf = 0; kf < 8; ++kf)
        wv[f][fc][kf] = *(const bf16x8*)(Wcat6 +
            (((size_t)(3 + f) * 256 + cw + fc * 16 + r16) * 256 + kf * 32 + hi16 * 8));
  float wd0 = att_w[cw + r16], wd1 = att_w[cw + 16 + r16];
  float attb = att_b[0];
  float thr = thrG[(size_t)b * 64 + lane];       // sorted esc (desc)
  if (t < 65) sigL[t] = sigG[(size_t)b * 65 + t];
  float bh0[2], bh1[2], bh2[2];
#pragma unroll
  for (int fc = 0; fc < 2; ++fc) {
    bh0[fc] = bhh[cw + fc * 16 + r16];
    bh1[fc] = bhh[256 + cw + fc * 16 + r16];
    bh2[fc] = bhh[512 + cw + fc * 16 + r16];
  }
  if (t < 256) {
    hbf[0][t] = enchB[((size_t)b * 64 + 63) * 256 + t];
    hbf[1][t] = __float2bfloat16(0.f);
  }
  float hp[2];
  hp[0] = __bfloat162float(enchB[((size_t)b * 64 + 63) * 256 + cw + r16]);
  hp[1] = __bfloat162float(enchB[((size_t)b * 64 + 63) * 256 + cw + 16 + r16]);
  if (hi16 == 0) {
    float pp = hp[0] * wd0 + hp[1] * wd1;
    pp += __shfl_xor(pp, 1, 64); pp += __shfl_xor(pp, 2, 64);
    pp += __shfl_xor(pp, 4, 64); pp += __shfl_xor(pp, 8, 64);
    if (lane == 0) psumL[0][w] = pp;
  }
  __syncthreads();
  const __hip_bfloat16* tpb = TP + (size_t)b * 65 * G3;
  const __hip_bfloat16* tqb = TQ + (size_t)b * 65 * G3;
  int bs3 = (b & 7) << 3;
  int cur = 0;
  for (int i = 0; i < NL; ++i) {
    // Gdec prefetch (in flight across the step)
    float gd0[2], gd1[2], gd2[2];
    if (hi16 == 0) {
      const float* gp = Gdec + ((size_t)i * 64 + b) * G3;
#pragma unroll
      for (int fc = 0; fc < 2; ++fc) {
        gd0[fc] = gp[cw + fc * 16 + r16];
        gd1[fc] = gp[256 + cw + fc * 16 + r16];
        gd2[fc] = gp[512 + cw + fc * 16 + r16];
      }
    }
    // pipelined p + delta + m (short chain)
    float4 pa = *(const float4*)&psumL[cur][0];
    float4 pb = *(const float4*)&psumL[cur][4];
    float d = ((pa.x + pa.y) + (pa.z + pa.w)) + ((pb.x + pb.y) + (pb.z + pb.w)) + attb;
    float ed = __expf(d);
    unsigned long long bal = __ballot(thr + d > 0.f);
    int m = __popcll(bal);
    // live table loads issued EARLY — L2 latency hides under the MFMAs below
    float tpr0[2], tpz0[2], tpn0[2], tqr0[2], tqz0[2], tqn0[2], sg = 0.f;
    if (hi16 == 0) {
      sg = sigL[m];
      const __hip_bfloat16* tpr = tpb + (size_t)m * G3;
      const __hip_bfloat16* tqr = tqb + (size_t)m * G3;
#pragma unroll
      for (int fc = 0; fc < 2; ++fc) {
        int c = cw + fc * 16 + r16;
        tpr0[fc] = __bfloat162float(tpr[c]);
        tpz0[fc] = __bfloat162float(tpr[256 + c]);
        tpn0[fc] = __bfloat162float(tpr[512 + c]);
        tqr0[fc] = __bfloat162float(tqr[c]);
        tqz0[fc] = __bfloat162float(tqr[256 + c]);
        tqn0[fc] = __bfloat162float(tqr[512 + c]);
      }
    }
    // gh MFMAs (h row-broadcast A-frags)
    const char* hb = (const char*)&hbf[cur][0];
    bf16x8 ah[8];
#pragma unroll
    for (int kf = 0; kf < 8; ++kf)
      ah[kf] = *(const bf16x8*)(hb + kf * 64 + hi16 * 16);
    f32x4 acch[3][2] = {};
#pragma unroll
    for (int f = 0; f < 3; ++f)
#pragma unroll
      for (int fc = 0; fc < 2; ++fc)
#pragma unroll
        for (int kf = 0; kf < 8; ++kf)
          acch[f][fc] = __builtin_amdgcn_mfma_f32_16x16x32_bf16(
              ah[kf], wv[f][fc][kf], acch[f][fc], 0, 0, 0);
    // gates + h update + next-step p partial (lanes<16)
    if (hi16 == 0) {
      float rn = 1.f / (ed * sg + (float)(64 - m));
      int nxt = cur ^ 1;
      float hn2[2];
#pragma unroll
      for (int fc = 0; fc < 2; ++fc) {
        int c = cw + fc * 16 + r16;
        float gir = (ed * tpr0[fc] + tqr0[fc]) * rn;
        float giz = (ed * tpz0[fc] + tqz0[fc]) * rn;
        float gin = (ed * tpn0[fc] + tqn0[fc]) * rn;
        float rr = 1.f / (1.f + __expf(-(gd0[fc] + gir + acch[0][fc][0] + bh0[fc])));
        float zz = 1.f / (1.f + __expf(-(gd1[fc] + giz + acch[1][fc][0] + bh1[fc])));
        float nn = fast_tanh(gd2[fc] + gin + rr * (acch[2][fc][0] + bh2[fc]));
        float hn = (1.f - zz) * nn + zz * hp[fc];
        hp[fc] = hn; hn2[fc] = hn;
        hbf[nxt][c] = __float2bfloat16(hn);
        int cs = (c & ~63) | ((c & 63) ^ bs3);
        dechb[((size_t)i * 64 + b) * 256 + cs] = __float2bfloat16(hn);
      }
      float pp = hn2[0] * wd0 + hn2[1] * wd1;
      pp += __shfl_xor(pp, 1, 64); pp += __shfl_xor(pp, 2, 64);
      pp += __shfl_xor(pp, 4, 64); pp += __shfl_xor(pp, 8, 64);
      if (lane == 0) psumL[cur ^ 1][w] = pp;
    }
    lds_barrier();
    cur ^= 1;
  }
}

// ---------------------------------------------------------------------------
// Log-softmax, register-resident single read + single write (one WG/row).
// ---------------------------------------------------------------------------
__global__ __launch_bounds__(256) void k_logsoftmax(float* __restrict__ out) {
  float* x = out + (size_t)blockIdx.x * NVOUT;
  __shared__ float red[256];
  int t = threadIdx.x;
  float4 v[10];
  float mx = -1e30f;
#pragma unroll
  for (int ii = 0; ii < 10; ++ii) {
    int slot = ii * 256 + t;
    if (slot < 2500) {
      v[ii] = *(const float4*)(x + slot * 4);
      mx = fmaxf(mx, fmaxf(fmaxf(v[ii].x, v[ii].y), fmaxf(v[ii].z, v[ii].w)));
    }
  }
  red[t] = mx; __syncthreads();
  for (int off = 128; off; off >>= 1) {
    if (t < off) red[t] = fmaxf(red[t], red[t + off]);
    __syncthreads();
  }
  mx = red[0]; __syncthreads();
  float sm = 0.f;
#pragma unroll
  for (int ii = 0; ii < 10; ++ii) {
    int slot = ii * 256 + t;
    if (slot < 2500)
      sm += __expf(v[ii].x - mx) + __expf(v[ii].y - mx)
          + __expf(v[ii].z - mx) + __expf(v[ii].w - mx);
  }
  red[t] = sm; __syncthreads();
  for (int off = 128; off; off >>= 1) {
    if (t < off) red[t] += red[t + off];
    __syncthreads();
  }
  float lse = mx + logf(red[0]);
#pragma unroll
  for (int ii = 0; ii < 10; ++ii) {
    int slot = ii * 256 + t;
    if (slot < 2500) {
      float4 o; o.x = v[ii].x - lse; o.y = v[ii].y - lse;
      o.z = v[ii].z - lse; o.w = v[ii].w - lse;
      *(float4*)(x + slot * 4) = o;
    }
  }
}

// ---------------------------------------------------------------------------
extern "C" void kernel_launch(void* const* d_in, const int* in_sizes, int n_in,
                              void* d_out, int out_size, void* d_ws, size_t ws_size,
                              hipStream_t stream) {
  const float* X        = (const float*)d_in[0];
  const int*   gt       = (const int*)  d_in[1];
  const float* enc_Wih  = (const float*)d_in[2];
  const float* enc_Whh  = (const float*)d_in[3];
  const float* enc_bih  = (const float*)d_in[4];
  const float* enc_bhh  = (const float*)d_in[5];
  const float* att_w    = (const float*)d_in[6];
  const float* att_b    = (const float*)d_in[7];
  const float* dec_Wih  = (const float*)d_in[8];
  const float* dec_Whh  = (const float*)d_in[9];
  const float* dec_bih  = (const float*)d_in[10];
  const float* dec_bhh  = (const float*)d_in[11];
  const float* out_W    = (const float*)d_in[12];
  const float* out_b    = (const float*)d_in[13];
  float* out = (float*)d_out;

  // workspace carve-up
  float* p = (float*)d_ws;
  float* Gienc  = p; p += NS * NB * G3;          // fp32, dead after encoder
  float* Gdec   = p; p += NL * NB * G3;          // fp32
  float* escoreT = p; p += NB * NS;
  __hip_bfloat16* q = (__hip_bfloat16*)p;
  __hip_bfloat16* enchBb = q; q += (size_t)NB * NS * NH;
  __hip_bfloat16* Wcat_e = q; q += (size_t)3 * 256 * 256;
  __hip_bfloat16* Wcat_d = q; q += (size_t)6 * 256 * 256;
  __hip_bfloat16* Xb     = q; q += (size_t)4096 * KP2;
  __hip_bfloat16* Wencb  = q; q += (size_t)G3 * KP2;
  __hip_bfloat16* Woutb  = q; q += (size_t)NOUTP * NH;
  __hip_bfloat16* dechb  = q; q += (size_t)NL * NB * NH;
  // ENCW [4096][768] bf16 (6.3 MB) aliases Gienc (12.6 MB, dead after encoder)
  __hip_bfloat16* ENCW   = (__hip_bfloat16*)Gienc;
  // attention tables alias Xb (84 MB, dead after k_gemm_encS)
  __hip_bfloat16* TP  = Xb;                               // 6.4 MB
  __hip_bfloat16* TQ  = Xb + (size_t)64 * 65 * G3;        // 6.4 MB
  float* thrG = (float*)(Xb + (size_t)2 * 64 * 65 * G3);
  float* sigG = thrG + 64 * 64;
  // split-K partials (50 MB fp32) in d_out scratch (overwritten later)
  float* Pout = (float*)d_out;

  // prep (independent)
  k_cvt_pad<<<4096, 256, 0, stream>>>(X, Xb, 4096, NVIN, KP2, 1);
  k_cvt_pad<<<G3, 256, 0, stream>>>(enc_Wih, Wencb, G3, NVIN, KP2, 1);
  k_cvt_pad<<<NOUTP, 256, 0, stream>>>(out_W, Woutb, NVOUT, NH, NH, 1);
  k_wpack<<<768, 256, 0, stream>>>(enc_Whh, NH, enc_Whh, NH, Wcat_e, 3 * 65536);
  k_wpack<<<1536, 256, 0, stream>>>(dec_Wih, NH + NVOUT, dec_Whh, NH, Wcat_d, 6 * 65536);
  k_pregather<<<NL * NB, 256, 0, stream>>>(dec_Wih, dec_bih, gt, Gdec);

  k_gemm_encS<<<dim3(6, 32, 4), 256, 0, stream>>>(Xb, Wencb, Pout);
  k_reduce4<<<3072, 256, 0, stream>>>((const float4*)Pout, enc_bih, (float4*)Gienc);
  k_encoder5<<<64, 512, 0, stream>>>(Gienc, Wcat_e, enc_bhh, enchBb);
  k_escoreB<<<1024, 256, 0, stream>>>(enchBb, att_w, escoreT);
  k_gemm_encw<<<dim3(6, 32), 256, 0, stream>>>(enchBb, Wcat_d, ENCW);
  k_tabs<<<64, 256, 0, stream>>>(ENCW, escoreT, TP, TQ, thrG, sigG);
  k_decoder8<<<64, 512, 0, stream>>>(Gdec, Wcat_d, dec_bhh, enchBb, TP, TQ,
                                     thrG, sigG, att_w, att_b, dechb);
  k_gemm_outS<<<dim3(79, 32), 256, 0, stream>>>(dechb, Woutb, out_b, out);
  k_logsoftmax<<<NB * NL, 256, 0, stream>>>(out);
}

// Round 16
// 679.199 us; speedup vs baseline: 2.2052x; 1.1462x over previous
//
#include <hip/hip_runtime.h>
#include <hip/hip_bf16.h>
#include <math.h>

// Problem dims (fixed by the reference)
#define NB 64      // batch
#define NS 64      // encoder steps
#define NL 64      // decoder steps
#define NH 256     // hidden
#define G3 768     // 3*NH (gates r,z,n)
#define NVIN 10000
#define NVOUT 10000
#define KP2 10240   // NVIN padded (4 splits x 40 x BK=64)
#define NOUTP 10112 // NVOUT padded to 128 for out GEMM

typedef __attribute__((ext_vector_type(8))) short bf16x8;  // 8 bf16 (4 VGPRs)
typedef __attribute__((ext_vector_type(4))) float f32x4;   // MFMA accumulator
typedef __attribute__((ext_vector_type(4))) unsigned int u32x4;

// async global->LDS, 16B per lane (dest must be wave-uniform base + lane*16)
__device__ __forceinline__ void gld_lds16(const __hip_bfloat16* g, __hip_bfloat16* l) {
  __builtin_amdgcn_global_load_lds(
      (const __attribute__((address_space(1))) unsigned int*)(const void*)g,
      (__attribute__((address_space(3))) unsigned int*)(void*)l, 16, 0, 0);
}

__device__ __forceinline__ unsigned int f2bf(float f) {  // RNE fp32->bf16 bits
  unsigned int u = __float_as_uint(f);
  return (u + 0x7fff + ((u >> 16) & 1)) >> 16;
}
__device__ __forceinline__ float bf2f(unsigned short u) {
  return __uint_as_float((unsigned)u << 16);
}
__device__ __forceinline__ float fast_tanh(float x) {   // tanh via v_exp_f32
  float e = __expf(-2.f * x);
  return (1.f - e) / (1.f + e);
}
// Workgroup barrier WITHOUT the vmcnt(0) drain __syncthreads() emits.
__device__ __forceinline__ void lds_barrier() {
  asm volatile("s_waitcnt lgkmcnt(0)\n\ts_barrier" ::: "memory");
}

// ---------------------------------------------------------------------------
// fp32 -> bf16 convert with padding; swz=1 pre-swizzles columns within each
// 64-group by ((row&7)<<3) (T2/m173: swizzle SOURCE, LDS dest linear).
// ---------------------------------------------------------------------------
__global__ __launch_bounds__(256) void k_cvt_pad(
    const float* __restrict__ in, __hip_bfloat16* __restrict__ out,
    int in_rows, int in_cols, int out_cols, int swz) {
  int r = blockIdx.x;
  const float* src = in + (size_t)r * in_cols;
  __hip_bfloat16* dst = out + (size_t)r * out_cols;
  bool live = r < in_rows;
  int sx = swz ? ((r & 7) << 3) : 0;
  for (int c = threadIdx.x * 4; c < out_cols; c += 1024) {
    int cc = (c & ~63) | ((c & 63) ^ sx);
    __hip_bfloat16 v[4];
    if (live && cc + 3 < in_cols) {
      float4 f = *(const float4*)(src + cc);
      v[0] = __float2bfloat16(f.x); v[1] = __float2bfloat16(f.y);
      v[2] = __float2bfloat16(f.z); v[3] = __float2bfloat16(f.w);
    } else {
      v[0] = v[1] = v[2] = v[3] = __float2bfloat16(0.f);
    }
    *(ushort4*)(dst + c) = *(const ushort4*)v;
  }
}

// ---------------------------------------------------------------------------
// Pack recurrent weights to bf16 Wcat[f][c][k].
// ---------------------------------------------------------------------------
__global__ __launch_bounds__(256) void k_wpack(
    const float* __restrict__ srcA, int strideA,
    const float* __restrict__ srcB, int strideB,
    __hip_bfloat16* __restrict__ out, int total) {
  int idx = blockIdx.x * 256 + threadIdx.x;
  if (idx >= total) return;
  int k = idx & 255, c = (idx >> 8) & 255, f = idx >> 16;
  float v = (f < 3) ? srcA[(size_t)(f * 256 + c) * strideA + k]
                    : srcB[(size_t)((f - 3) * 256 + c) * strideB + k];
  out[idx] = __float2bfloat16(v);
}

// ---------------------------------------------------------------------------
// Enc GEMM, split-K (see R7): P[z] partials, reduced by k_reduce4.
// ---------------------------------------------------------------------------
__global__ __launch_bounds__(256) void k_gemm_encS(
    const __hip_bfloat16* __restrict__ A, const __hip_bfloat16* __restrict__ B,
    float* __restrict__ P) {
  __shared__ __hip_bfloat16 As[128][64];
  __shared__ __hip_bfloat16 Bs[128][64];
  int t = threadIdx.x;
  int wid = t >> 6, lane = t & 63;
  int m0 = blockIdx.y * 128, n0 = blockIdx.x * 128;
  int wr = wid >> 1, wc = wid & 1;
  int r16 = lane & 15, hi16 = lane >> 4;
  int xr = (r16 & 7) << 4;
  f32x4 acc[4][4] = {};
  int kbeg = blockIdx.z * 2560;
  for (int ks = 0; ks < 40; ++ks) {
    int k0 = kbeg + ks * 64;
    __syncthreads();
#pragma unroll
    for (int is = 0; is < 4; ++is) {
      int off = is * 4096 + t * 16;
      int r = off >> 7, e = (off & 127) >> 1;
      gld_lds16(A + (size_t)(m0 + r) * KP2 + k0 + e, &As[r][e]);
      gld_lds16(B + (size_t)(n0 + r) * KP2 + k0 + e, &Bs[r][e]);
    }
    __syncthreads();
    const char* ab = (const char*)As;
    const char* bb = (const char*)Bs;
#pragma unroll
    for (int kk = 0; kk < 2; ++kk) {
      int ko = kk * 64 + hi16 * 16;
      bf16x8 af[4], bfr[4];
#pragma unroll
      for (int i = 0; i < 4; ++i) {
        af[i]  = *(const bf16x8*)(ab + (wr * 64 + i * 16 + r16) * 128 + (ko ^ xr));
        bfr[i] = *(const bf16x8*)(bb + (wc * 64 + i * 16 + r16) * 128 + (ko ^ xr));
      }
#pragma unroll
      for (int i = 0; i < 4; ++i)
#pragma unroll
        for (int j = 0; j < 4; ++j)
          acc[i][j] = __builtin_amdgcn_mfma_f32_16x16x32_bf16(af[i], bfr[j], acc[i][j], 0, 0, 0);
    }
  }
  float* Pz = P + (size_t)blockIdx.z * 4096 * G3;
#pragma unroll
  for (int i = 0; i < 4; ++i)
#pragma unroll
    for (int j = 0; j < 4; ++j) {
      int ccol = n0 + wc * 64 + j * 16 + r16;
#pragma unroll
      for (int q = 0; q < 4; ++q) {
        int crow = m0 + wr * 64 + i * 16 + hi16 * 4 + q;
        Pz[(size_t)crow * G3 + ccol] = acc[i][j][q];
      }
    }
}

// Gienc = P0+P1+P2+P3 + bias  (fp32)
__global__ __launch_bounds__(256) void k_reduce4(
    const float4* __restrict__ P, const float* __restrict__ bias,
    float4* __restrict__ G) {
  int idx = blockIdx.x * 256 + threadIdx.x;
  float4 a = P[idx], b = P[idx + 786432], c = P[idx + 2 * 786432],
         d = P[idx + 3 * 786432];
  float4 bs = *(const float4*)(bias + (idx % 192) * 4);
  float4 o;
  o.x = a.x + b.x + c.x + d.x + bs.x;
  o.y = a.y + b.y + c.y + d.y + bs.y;
  o.z = a.z + b.z + c.z + d.z + bs.z;
  o.w = a.w + b.w + c.w + d.w + bs.w;
  G[idx] = o;
}

// ---------------------------------------------------------------------------
// Out GEMM (BK=64 + swizzle): writes BF16 logits (+bias) to a workspace
// scratch buffer (NOT d_out — cross-block write/read aliasing there raced,
// R15 NaN). Log-softmax converts to fp32. Terminal rounding only.
// ---------------------------------------------------------------------------
__global__ __launch_bounds__(256) void k_gemm_outS(
    const __hip_bfloat16* __restrict__ A, const __hip_bfloat16* __restrict__ B,
    const float* __restrict__ bias, __hip_bfloat16* __restrict__ Lb) {
  __shared__ __hip_bfloat16 As[128][64];
  __shared__ __hip_bfloat16 Bs[128][64];
  int t = threadIdx.x;
  int wid = t >> 6, lane = t & 63;
  int m0 = blockIdx.y * 128, n0 = blockIdx.x * 128;
  int wr = wid >> 1, wc = wid & 1;
  int r16 = lane & 15, hi16 = lane >> 4;
  int xr = (r16 & 7) << 4;
  f32x4 acc[4][4] = {};
  for (int k0 = 0; k0 < NH; k0 += 64) {
    __syncthreads();
#pragma unroll
    for (int is = 0; is < 4; ++is) {
      int off = is * 4096 + t * 16;
      int r = off >> 7, e = (off & 127) >> 1;
      gld_lds16(A + (size_t)(m0 + r) * NH + k0 + e, &As[r][e]);
      gld_lds16(B + (size_t)(n0 + r) * NH + k0 + e, &Bs[r][e]);
    }
    __syncthreads();
    const char* ab = (const char*)As;
    const char* bb = (const char*)Bs;
#pragma unroll
    for (int kk = 0; kk < 2; ++kk) {
      int ko = kk * 64 + hi16 * 16;
      bf16x8 af[4], bfr[4];
#pragma unroll
      for (int i = 0; i < 4; ++i) {
        af[i]  = *(const bf16x8*)(ab + (wr * 64 + i * 16 + r16) * 128 + (ko ^ xr));
        bfr[i] = *(const bf16x8*)(bb + (wc * 64 + i * 16 + r16) * 128 + (ko ^ xr));
      }
#pragma unroll
      for (int i = 0; i < 4; ++i)
#pragma unroll
        for (int j = 0; j < 4; ++j)
          acc[i][j] = __builtin_amdgcn_mfma_f32_16x16x32_bf16(af[i], bfr[j], acc[i][j], 0, 0, 0);
    }
  }
#pragma unroll
  for (int i = 0; i < 4; ++i)
#pragma unroll
    for (int j = 0; j < 4; ++j) {
      int ccol = n0 + wc * 64 + j * 16 + r16;
      if (ccol < NVOUT) {
        float bs = bias[ccol];
#pragma unroll
        for (int q = 0; q < 4; ++q) {
          int crow = m0 + wr * 64 + i * 16 + hi16 * 4 + q;  // = l*64+b
          int l = crow >> 6, b = crow & 63;
          Lb[((size_t)b * NL + l) * NVOUT + ccol] = __float2bfloat16(acc[i][j][q] + bs);
        }
      }
    }
}

// ---------------------------------------------------------------------------
// ENCW GEMM (plain rows): ENCW[b*64+s][c] = sum_k ench[b*64+s][k]*Wih_ctx[c][k]
// ---------------------------------------------------------------------------
__global__ __launch_bounds__(256) void k_gemm_encw(
    const __hip_bfloat16* __restrict__ A, const __hip_bfloat16* __restrict__ B,
    __hip_bfloat16* __restrict__ C) {
  __shared__ __hip_bfloat16 As[128][32];
  __shared__ __hip_bfloat16 Bs[128][32];
  int t = threadIdx.x;
  int wid = t >> 6, lane = t & 63;
  int m0 = blockIdx.y * 128, n0 = blockIdx.x * 128;
  int wr = wid >> 1, wc = wid & 1;
  f32x4 acc[4][4] = {};
  for (int k0 = 0; k0 < NH; k0 += 32) {
    __syncthreads();
#pragma unroll
    for (int is = 0; is < 2; ++is) {
      int off = is * 4096 + wid * 1024 + lane * 16;
      int r = off >> 6, cb = (off & 63) >> 1;
      gld_lds16(A + (size_t)(m0 + r) * NH + k0 + cb, &As[r][cb]);
      gld_lds16(B + (size_t)(n0 + r) * NH + k0 + cb, &Bs[r][cb]);
    }
    __syncthreads();
    int r16 = lane & 15, kb = (lane >> 4) * 8;
    bf16x8 af[4], bfr[4];
#pragma unroll
    for (int i = 0; i < 4; ++i) {
      af[i]  = *(const bf16x8*)&As[wr * 64 + i * 16 + r16][kb];
      bfr[i] = *(const bf16x8*)&Bs[wc * 64 + i * 16 + r16][kb];
    }
#pragma unroll
    for (int i = 0; i < 4; ++i)
#pragma unroll
      for (int j = 0; j < 4; ++j)
        acc[i][j] = __builtin_amdgcn_mfma_f32_16x16x32_bf16(af[i], bfr[j], acc[i][j], 0, 0, 0);
  }
  int r16 = lane & 15, rg = lane >> 4;
#pragma unroll
  for (int i = 0; i < 4; ++i)
#pragma unroll
    for (int j = 0; j < 4; ++j) {
      int ccol = n0 + wc * 64 + j * 16 + r16;
#pragma unroll
      for (int q = 0; q < 4; ++q) {
        int crow = m0 + wr * 64 + i * 16 + rg * 4 + q;   // = b*64+s
        C[(size_t)crow * G3 + ccol] = __float2bfloat16(acc[i][j][q]);
      }
    }
}

// ---------------------------------------------------------------------------
// Attention prefix tables (gi(δ) collapse — see R12).
// ---------------------------------------------------------------------------
__global__ __launch_bounds__(256) void k_tabs(
    const __hip_bfloat16* __restrict__ ENCW, const float* __restrict__ escoreT,
    __hip_bfloat16* __restrict__ TP, __hip_bfloat16* __restrict__ TQ,
    float* __restrict__ thrG, float* __restrict__ sigG) {
  __shared__ float thrL[64];
  __shared__ int   idxL[64];
  __shared__ float wexpL[64];
  int b = blockIdx.x, t = threadIdx.x;
  if (t < 64) {   // rank-sort (desc, index tiebreak)
    float mine = escoreT[b * 64 + t];
    int rank = 0;
    for (int j = 0; j < 64; ++j) {
      float v = __shfl(mine, j, 64);
      rank += (v > mine) || (v == mine && j < t);
    }
    thrL[rank] = mine;
    idxL[rank] = t;
  }
  __syncthreads();
  if (t < 64) {
    float e = __expf(thrL[t]);
    wexpL[t] = e;
    float s = e;
    for (int off = 1; off < 64; off <<= 1) {
      float o = __shfl_up(s, off, 64);
      if (t >= off) s += o;
    }
    sigG[b * 65 + t + 1] = s;
    if (t == 0) sigG[b * 65] = 0.f;
    thrG[b * 64 + t] = thrL[t];
  }
  __syncthreads();
#pragma unroll
  for (int cc = 0; cc < 3; ++cc) {
    int c = t + cc * 256;
    const __hip_bfloat16* ep = ENCW + (size_t)b * 64 * G3 + c;
    float T = 0.f;
    for (int s = 0; s < 64; ++s) T += __bfloat162float(ep[(size_t)s * G3]);
    float P = 0.f, U = 0.f;
    __hip_bfloat16* tp = TP + (size_t)b * 65 * G3 + c;
    __hip_bfloat16* tq = TQ + (size_t)b * 65 * G3 + c;
    tp[0] = __float2bfloat16(0.f);
    tq[0] = __float2bfloat16(T);
    for (int m = 1; m <= 64; ++m) {
      int j = idxL[m - 1];
      float e = __bfloat162float(ep[(size_t)j * G3]);
      P += wexpL[m - 1] * e;
      U += e;
      tp[(size_t)m * G3] = __float2bfloat16(P);
      tq[(size_t)m * G3] = __float2bfloat16(T - U);
    }
  }
}

// ---------------------------------------------------------------------------
// Pre-gather decoder one-hot input term (fp32): Gdec = bih + onehot column.
// ---------------------------------------------------------------------------
__global__ __launch_bounds__(256) void k_pregather(
    const float* __restrict__ Wih, const float* __restrict__ bih,
    const int* __restrict__ gt, float* __restrict__ Gdec) {
  int ib = blockIdx.x;              // i*64+b
  int i = ib >> 6, b = ib & 63;
  int tok = (i > 0) ? gt[b * NL + (i - 1)] : -1;
  for (int g = threadIdx.x; g < G3; g += 256) {
    float v = bih[g];
    if (tok >= 0) v += Wih[(size_t)g * (NH + NVOUT) + NH + tok];
    Gdec[(size_t)ib * G3 + g] = v;
  }
}

// ---------------------------------------------------------------------------
// Encoder scan v5 (R11/R12 known-good): 64 WGs x 512 thr, one batch/WG.
// ---------------------------------------------------------------------------
__global__ __launch_bounds__(512) void k_encoder5(
    const float* __restrict__ Gi, const __hip_bfloat16* __restrict__ Wcat,
    const float* __restrict__ bhh, __hip_bfloat16* __restrict__ enchB) {
  __shared__ __hip_bfloat16 hbf[2][256];
  int t = threadIdx.x, w = t >> 6, lane = t & 63;
  int b = blockIdx.x;
  int r16 = lane & 15, hi16 = lane >> 4;
  int cw = w * 32;
  bf16x8 wv[3][2][8];
#pragma unroll
  for (int f = 0; f < 3; ++f)
#pragma unroll
    for (int fc = 0; fc < 2; ++fc)
#pragma unroll
      for (int kf = 0; kf < 8; ++kf)
        wv[f][fc][kf] = *(const bf16x8*)(Wcat +
            (((size_t)f * 256 + cw + fc * 16 + r16) * 256 + kf * 32 + hi16 * 8));
  float bh0[2], bh1[2], bh2[2];
#pragma unroll
  for (int fc = 0; fc < 2; ++fc) {
    bh0[fc] = bhh[cw + fc * 16 + r16];
    bh1[fc] = bhh[256 + cw + fc * 16 + r16];
    bh2[fc] = bhh[512 + cw + fc * 16 + r16];
  }
  if (t < 256) {
    hbf[0][t] = __float2bfloat16(0.f);
    hbf[1][t] = __float2bfloat16(0.f);
  }
  __syncthreads();
  float hp[2] = {0.f, 0.f};
  int cur = 0;
  for (int s = 0; s < NS; ++s) {
    float gd0[2], gd1[2], gd2[2];
    if (hi16 == 0) {
      const float* gp = Gi + ((size_t)b * 64 + s) * G3;
#pragma unroll
      for (int fc = 0; fc < 2; ++fc) {
        gd0[fc] = gp[cw + fc * 16 + r16];
        gd1[fc] = gp[256 + cw + fc * 16 + r16];
        gd2[fc] = gp[512 + cw + fc * 16 + r16];
      }
    }
    const char* hb = (const char*)&hbf[cur][0];
    f32x4 acc[3][2] = {};
#pragma unroll
    for (int half = 0; half < 2; ++half) {
      bf16x8 ah[4];
#pragma unroll
      for (int kf = 0; kf < 4; ++kf)
        ah[kf] = *(const bf16x8*)(hb + (half * 4 + kf) * 64 + hi16 * 16);  // broadcast
#pragma unroll
      for (int f = 0; f < 3; ++f)
#pragma unroll
        for (int fc = 0; fc < 2; ++fc)
#pragma unroll
          for (int kf = 0; kf < 4; ++kf)
            acc[f][fc] = __builtin_amdgcn_mfma_f32_16x16x32_bf16(
                ah[kf], wv[f][fc][half * 4 + kf], acc[f][fc], 0, 0, 0);
    }
    if (hi16 == 0) {
      int nxt = cur ^ 1;
#pragma unroll
      for (int fc = 0; fc < 2; ++fc) {
        int c = cw + fc * 16 + r16;
        float rr = 1.f / (1.f + __expf(-(gd0[fc] + acc[0][fc][0] + bh0[fc])));
        float zz = 1.f / (1.f + __expf(-(gd1[fc] + acc[1][fc][0] + bh1[fc])));
        float nn = fast_tanh(gd2[fc] + rr * (acc[2][fc][0] + bh2[fc]));
        float hn = (1.f - zz) * nn + zz * hp[fc];
        hp[fc] = hn;
        hbf[nxt][c] = __float2bfloat16(hn);
        enchB[((size_t)b * 64 + s) * 256 + c] = __float2bfloat16(hn);
      }
    }
    lds_barrier();
    cur ^= 1;
  }
}

// escoreT[b*64+s] = enc_h[b][s] . w_enc
__global__ __launch_bounds__(256) void k_escoreB(
    const __hip_bfloat16* __restrict__ enchB, const float* __restrict__ att_w,
    float* __restrict__ escoreT) {
  int row = blockIdx.x * 4 + (threadIdx.x >> 6);   // = b*64+s
  int lane = threadIdx.x & 63;
  ushort4 u = *(const ushort4*)(enchB + (size_t)row * 256 + lane * 4);
  const float* we = att_w + 256 + lane * 4;
  float p = bf2f(u.x) * we[0] + bf2f(u.y) * we[1]
          + bf2f(u.z) * we[2] + bf2f(u.w) * we[3];
#pragma unroll
  for (int off = 32; off; off >>= 1) p += __shfl_xor(p, off, 64);
  if (lane == 0) escoreT[row] = p;
}

// ---------------------------------------------------------------------------
// Decoder scan v8 — EXACT R12 body (empirically 181 us; R14's load-hoist
// regressed it: early partial loads double as cache-line prefetch and the
// live loads after the MFMAs keep MFMA issue unblocked).
// ---------------------------------------------------------------------------
__global__ __launch_bounds__(512) void k_decoder8(
    const float* __restrict__ Gdec, const __hip_bfloat16* __restrict__ Wcat6,
    const float* __restrict__ bhh, const __hip_bfloat16* __restrict__ enchB,
    const __hip_bfloat16* __restrict__ TP, const __hip_bfloat16* __restrict__ TQ,
    const float* __restrict__ thrG, const float* __restrict__ sigG,
    const float* __restrict__ att_w, const float* __restrict__ att_b,
    __hip_bfloat16* __restrict__ dechb) {
  __shared__ __hip_bfloat16 hbf[2][256];
  __shared__ float psumL[2][8];
  __shared__ float sigL[65];
  int t = threadIdx.x, w = t >> 6, lane = t & 63;
  int b = blockIdx.x;
  int r16 = lane & 15, hi16 = lane >> 4;
  int cw = w * 32;
  // all 3 Whh panels resident (panels 3,4,5 of Wcat6)
  bf16x8 wv[3][2][8];
#pragma unroll
  for (int f = 0; f < 3; ++f)
#pragma unroll
    for (int fc = 0; fc < 2; ++fc)
#pragma unroll
      for (int kf = 0; kf < 8; ++kf)
        wv[f][fc][kf] = *(const bf16x8*)(Wcat6 +
            (((size_t)(3 + f) * 256 + cw + fc * 16 + r16) * 256 + kf * 32 + hi16 * 8));
  float wd0 = att_w[cw + r16], wd1 = att_w[cw + 16 + r16];
  float attb = att_b[0];
  float thr = thrG[(size_t)b * 64 + lane];       // sorted esc (desc)
  if (t < 65) sigL[t] = sigG[(size_t)b * 65 + t];
  float bh0[2], bh1[2], bh2[2];
#pragma unroll
  for (int fc = 0; fc < 2; ++fc) {
    bh0[fc] = bhh[cw + fc * 16 + r16];
    bh1[fc] = bhh[256 + cw + fc * 16 + r16];
    bh2[fc] = bhh[512 + cw + fc * 16 + r16];
  }
  if (t < 256) {
    hbf[0][t] = enchB[((size_t)b * 64 + 63) * 256 + t];
    hbf[1][t] = __float2bfloat16(0.f);
  }
  float hp[2];
  hp[0] = __bfloat162float(enchB[((size_t)b * 64 + 63) * 256 + cw + r16]);
  hp[1] = __bfloat162float(enchB[((size_t)b * 64 + 63) * 256 + cw + 16 + r16]);
  if (hi16 == 0) {
    float pp = hp[0] * wd0 + hp[1] * wd1;
    pp += __shfl_xor(pp, 1, 64); pp += __shfl_xor(pp, 2, 64);
    pp += __shfl_xor(pp, 4, 64); pp += __shfl_xor(pp, 8, 64);
    if (lane == 0) psumL[0][w] = pp;
  }
  __syncthreads();
  const __hip_bfloat16* tpb = TP + (size_t)b * 65 * G3;
  const __hip_bfloat16* tqb = TQ + (size_t)b * 65 * G3;
  int bs3 = (b & 7) << 3;
  int cur = 0;
  for (int i = 0; i < NL; ++i) {
    // Gdec prefetch (in flight across the step)
    float gd0[2], gd1[2], gd2[2];
    if (hi16 == 0) {
      const float* gp = Gdec + ((size_t)i * 64 + b) * G3;
#pragma unroll
      for (int fc = 0; fc < 2; ++fc) {
        gd0[fc] = gp[cw + fc * 16 + r16];
        gd1[fc] = gp[256 + cw + fc * 16 + r16];
        gd2[fc] = gp[512 + cw + fc * 16 + r16];
      }
    }
    // pipelined p + delta + m (short chain)
    float4 pa = *(const float4*)&psumL[cur][0];
    float4 pb = *(const float4*)&psumL[cur][4];
    float d = ((pa.x + pa.y) + (pa.z + pa.w)) + ((pb.x + pb.y) + (pb.z + pb.w)) + attb;
    float ed = __expf(d);
    unsigned long long bal = __ballot(thr + d > 0.f);
    int m = __popcll(bal);
    // table loads (L2, hidden under the gh MFMAs below)
    float tp0 = 0.f, tp1 = 0.f, tq0 = 0.f, tq1 = 0.f, sg = 0.f;
    if (hi16 == 0) {
      const __hip_bfloat16* tpr = tpb + (size_t)m * G3 + cw + r16;
      const __hip_bfloat16* tqr = tqb + (size_t)m * G3 + cw + r16;
      tp0 = __bfloat162float(tpr[0]);  tp1 = __bfloat162float(tpr[16]);
      tq0 = __bfloat162float(tqr[0]);  tq1 = __bfloat162float(tqr[16]);
      sg = sigL[m];
    }
    // gh MFMAs (h row-broadcast A-frags)
    const char* hb = (const char*)&hbf[cur][0];
    bf16x8 ah[8];
#pragma unroll
    for (int kf = 0; kf < 8; ++kf)
      ah[kf] = *(const bf16x8*)(hb + kf * 64 + hi16 * 16);
    f32x4 acch[3][2] = {};
#pragma unroll
    for (int f = 0; f < 3; ++f)
#pragma unroll
      for (int fc = 0; fc < 2; ++fc)
#pragma unroll
        for (int kf = 0; kf < 8; ++kf)
          acch[f][fc] = __builtin_amdgcn_mfma_f32_16x16x32_bf16(
              ah[kf], wv[f][fc][kf], acch[f][fc], 0, 0, 0);
    // gates + h update + next-step p partial (lanes<16)
    if (hi16 == 0) {
      float rn = 1.f / (ed * sg + (float)(64 - m));
      float gi0 = (ed * tp0 + tq0) * rn;
      float gi1 = (ed * tp1 + tq1) * rn;
      int nxt = cur ^ 1;
      float hn2[2];
#pragma unroll
      for (int fc = 0; fc < 2; ++fc) {
        int c = cw + fc * 16 + r16;
        float gi = fc ? gi1 : gi0;
        (void)gi;
        (void)c;
      }
      // per-panel table values: r gate at c, z at 256+c, n at 512+c
      float tpr0[2], tpz0[2], tpn0[2], tqr0[2], tqz0[2], tqn0[2];
#pragma unroll
      for (int fc = 0; fc < 2; ++fc) {
        int c = cw + fc * 16 + r16;
        tpr0[fc] = __bfloat162float(tpb[(size_t)m * G3 + c]);
        tpz0[fc] = __bfloat162float(tpb[(size_t)m * G3 + 256 + c]);
        tpn0[fc] = __bfloat162float(tpb[(size_t)m * G3 + 512 + c]);
        tqr0[fc] = __bfloat162float(tqb[(size_t)m * G3 + c]);
        tqz0[fc] = __bfloat162float(tqb[(size_t)m * G3 + 256 + c]);
        tqn0[fc] = __bfloat162float(tqb[(size_t)m * G3 + 512 + c]);
      }
#pragma unroll
      for (int fc = 0; fc < 2; ++fc) {
        int c = cw + fc * 16 + r16;
        float gir = (ed * tpr0[fc] + tqr0[fc]) * rn;
        float giz = (ed * tpz0[fc] + tqz0[fc]) * rn;
        float gin = (ed * tpn0[fc] + tqn0[fc]) * rn;
        float rr = 1.f / (1.f + __expf(-(gd0[fc] + gir + acch[0][fc][0] + bh0[fc])));
        float zz = 1.f / (1.f + __expf(-(gd1[fc] + giz + acch[1][fc][0] + bh1[fc])));
        float nn = fast_tanh(gd2[fc] + gin + rr * (acch[2][fc][0] + bh2[fc]));
        float hn = (1.f - zz) * nn + zz * hp[fc];
        hp[fc] = hn; hn2[fc] = hn;
        hbf[nxt][c] = __float2bfloat16(hn);
        int cs = (c & ~63) | ((c & 63) ^ bs3);
        dechb[((size_t)i * 64 + b) * 256 + cs] = __float2bfloat16(hn);
      }
      float pp = hn2[0] * wd0 + hn2[1] * wd1;
      pp += __shfl_xor(pp, 1, 64); pp += __shfl_xor(pp, 2, 64);
      pp += __shfl_xor(pp, 4, 64); pp += __shfl_xor(pp, 8, 64);
      if (lane == 0) psumL[cur ^ 1][w] = pp;
    }
    lds_barrier();
    cur ^= 1;
  }
}

// ---------------------------------------------------------------------------
// Log-softmax: reads BF16 logits (workspace), writes fp32 to d_out.
// Disjoint buffers — no cross-block aliasing (R15 lesson).
// ---------------------------------------------------------------------------
__global__ __launch_bounds__(256) void k_logsoftmax(
    const __hip_bfloat16* __restrict__ in, float* __restrict__ out) {
  const __hip_bfloat16* xi = in + (size_t)blockIdx.x * NVOUT;
  float* xo = out + (size_t)blockIdx.x * NVOUT;
  __shared__ float red[256];
  int t = threadIdx.x;
  ushort4 v[10];
  float mx = -1e30f;
#pragma unroll
  for (int ii = 0; ii < 10; ++ii) {
    int slot = ii * 256 + t;
    if (slot < 2500) {
      v[ii] = *(const ushort4*)(xi + slot * 4);
      mx = fmaxf(mx, fmaxf(fmaxf(bf2f(v[ii].x), bf2f(v[ii].y)),
                           fmaxf(bf2f(v[ii].z), bf2f(v[ii].w))));
    }
  }
  red[t] = mx; __syncthreads();
  for (int off = 128; off; off >>= 1) {
    if (t < off) red[t] = fmaxf(red[t], red[t + off]);
    __syncthreads();
  }
  mx = red[0]; __syncthreads();
  float sm = 0.f;
#pragma unroll
  for (int ii = 0; ii < 10; ++ii) {
    int slot = ii * 256 + t;
    if (slot < 2500)
      sm += __expf(bf2f(v[ii].x) - mx) + __expf(bf2f(v[ii].y) - mx)
          + __expf(bf2f(v[ii].z) - mx) + __expf(bf2f(v[ii].w) - mx);
  }
  red[t] = sm; __syncthreads();
  for (int off = 128; off; off >>= 1) {
    if (t < off) red[t] += red[t + off];
    __syncthreads();
  }
  float lse = mx + logf(red[0]);
#pragma unroll
  for (int ii = 0; ii < 10; ++ii) {
    int slot = ii * 256 + t;
    if (slot < 2500) {
      float4 o;
      o.x = bf2f(v[ii].x) - lse; o.y = bf2f(v[ii].y) - lse;
      o.z = bf2f(v[ii].z) - lse; o.w = bf2f(v[ii].w) - lse;
      *(float4*)(xo + slot * 4) = o;
    }
  }
}

// ---------------------------------------------------------------------------
extern "C" void kernel_launch(void* const* d_in, const int* in_sizes, int n_in,
                              void* d_out, int out_size, void* d_ws, size_t ws_size,
                              hipStream_t stream) {
  const float* X        = (const float*)d_in[0];
  const int*   gt       = (const int*)  d_in[1];
  const float* enc_Wih  = (const float*)d_in[2];
  const float* enc_Whh  = (const float*)d_in[3];
  const float* enc_bih  = (const float*)d_in[4];
  const float* enc_bhh  = (const float*)d_in[5];
  const float* att_w    = (const float*)d_in[6];
  const float* att_b    = (const float*)d_in[7];
  const float* dec_Wih  = (const float*)d_in[8];
  const float* dec_Whh  = (const float*)d_in[9];
  const float* dec_bih  = (const float*)d_in[10];
  const float* dec_bhh  = (const float*)d_in[11];
  const float* out_W    = (const float*)d_in[12];
  const float* out_b    = (const float*)d_in[13];
  float* out = (float*)d_out;

  // workspace carve-up
  float* p = (float*)d_ws;
  float* Gienc  = p; p += NS * NB * G3;          // fp32, dead after encoder
  float* Gdec   = p; p += NL * NB * G3;          // fp32
  float* escoreT = p; p += NB * NS;
  __hip_bfloat16* q = (__hip_bfloat16*)p;
  __hip_bfloat16* enchBb = q; q += (size_t)NB * NS * NH;
  __hip_bfloat16* Wcat_e = q; q += (size_t)3 * 256 * 256;
  __hip_bfloat16* Wcat_d = q; q += (size_t)6 * 256 * 256;
  __hip_bfloat16* Xb     = q; q += (size_t)4096 * KP2;    // 83.9 MB
  __hip_bfloat16* Wencb  = q; q += (size_t)G3 * KP2;      // 15.7 MB (contiguous after Xb)
  __hip_bfloat16* Woutb  = q; q += (size_t)NOUTP * NH;
  __hip_bfloat16* dechb  = q; q += (size_t)NL * NB * NH;
  // ENCW [4096][768] bf16 (6.3 MB) aliases Gienc (12.6 MB, dead after encoder)
  __hip_bfloat16* ENCW   = (__hip_bfloat16*)Gienc;
  // Xb+Wencb region (99.6 MB) is dead after k_gemm_encS. Tables take the
  // first ~12.9 MB; bf16 logits Lb (81.92 MB) sit at +16 MB — disjoint from
  // the tables AND from d_out (R15's cross-block race is gone).
  __hip_bfloat16* TP  = Xb;                               // 6.4 MB
  __hip_bfloat16* TQ  = Xb + (size_t)64 * 65 * G3;        // 6.4 MB
  float* thrG = (float*)(Xb + (size_t)2 * 64 * 65 * G3);  // 16 KB
  float* sigG = thrG + 64 * 64;                           // 16.6 KB
  __hip_bfloat16* Lb = Xb + (size_t)8 * 1024 * 1024;      // +16 MB, 81.92 MB
  // split-K partials (50 MB fp32) in d_out scratch (fully overwritten by
  // k_logsoftmax's fp32 output later — no concurrent aliasing)
  float* Pout = (float*)d_out;

  // prep (independent)
  k_cvt_pad<<<4096, 256, 0, stream>>>(X, Xb, 4096, NVIN, KP2, 1);
  k_cvt_pad<<<G3, 256, 0, stream>>>(enc_Wih, Wencb, G3, NVIN, KP2, 1);
  k_cvt_pad<<<NOUTP, 256, 0, stream>>>(out_W, Woutb, NVOUT, NH, NH, 1);
  k_wpack<<<768, 256, 0, stream>>>(enc_Whh, NH, enc_Whh, NH, Wcat_e, 3 * 65536);
  k_wpack<<<1536, 256, 0, stream>>>(dec_Wih, NH + NVOUT, dec_Whh, NH, Wcat_d, 6 * 65536);
  k_pregather<<<NL * NB, 256, 0, stream>>>(dec_Wih, dec_bih, gt, Gdec);

  k_gemm_encS<<<dim3(6, 32, 4), 256, 0, stream>>>(Xb, Wencb, Pout);
  k_reduce4<<<3072, 256, 0, stream>>>((const float4*)Pout, enc_bih, (float4*)Gienc);
  k_encoder5<<<64, 512, 0, stream>>>(Gienc, Wcat_e, enc_bhh, enchBb);
  k_escoreB<<<1024, 256, 0, stream>>>(enchBb, att_w, escoreT);
  k_gemm_encw<<<dim3(6, 32), 256, 0, stream>>>(enchBb, Wcat_d, ENCW);
  k_tabs<<<64, 256, 0, stream>>>(ENCW, escoreT, TP, TQ, thrG, sigG);
  k_decoder8<<<64, 512, 0, stream>>>(Gdec, Wcat_d, dec_bhh, enchBb, TP, TQ,
                                     thrG, sigG, att_w, att_b, dechb);
  k_gemm_outS<<<dim3(79, 32), 256, 0, stream>>>(dechb, Woutb, out_b, Lb);
  k_logsoftmax<<<NB * NL, 256, 0, stream>>>(Lb, out);
}